// Round 2
// baseline (281.129 us; speedup 1.0000x reference)
//
#include <hip/hip_runtime.h>
#include <math.h>

#define B_ 8
#define C_ 256
#define HW_ 4096
#define JP_ 1024
#define EPS_ 1e-5f

typedef __attribute__((ext_vector_type(8))) short bf16x8;   // 8 bf16 (4 VGPR) MFMA frag
typedef __attribute__((ext_vector_type(4))) short short4v;  // 8B packed bf16 store
typedef __attribute__((ext_vector_type(4))) float f32x4;    // MFMA accumulator
typedef unsigned short ushort_t;
typedef unsigned int uint_t;

__device__ __forceinline__ ushort_t f2bf(float f) {
    uint_t u = __float_as_uint(f);
    u += 0x7fffu + ((u >> 16) & 1u);       // round-nearest-even
    return (ushort_t)(u >> 16);
}
__device__ __forceinline__ float bf2f(ushort_t h) {
    return __uint_as_float(((uint_t)h) << 16);
}

// ---------------- workspace layout (bytes) ----------------
// xn  f32 [b][c][i]      33554432
// xnb bf16 [b][i][c]     16777216   (aliased by AOt after q-GEMM consumes it)
// xnpb bf16 [b][j][c]     4194304
// Qt  bf16 [b][i][c]     16777216   (pre-scaled by 1/16)
// Kt  bf16 [b][j][c]      4194304
// Vb  bf16 [b][c][j]      4194304
// wqb/wpb bf16 weights     524288
// sums/stat                  128
static const size_t OFF_XN   = 0;
static const size_t OFF_XNB  = 33554432;
static const size_t OFF_AOT  = OFF_XNB;          // alias: xnb dead after q-GEMM
static const size_t OFF_XNPB = 50331648;
static const size_t OFF_QT   = 54525952;
static const size_t OFF_KT   = 71303168;
static const size_t OFF_VB   = 75497472;
static const size_t OFF_WQB  = 79691776;
static const size_t OFF_WPB  = 80084992;
static const size_t OFF_SUM  = 80216064;
static const size_t OFF_STAT = 80216128;

// ---------------- K0: fp32 -> bf16 weight convert ----------------
__global__ __launch_bounds__(256) void k_cvt(const float* __restrict__ src,
                                             ushort_t* __restrict__ dst, int n4) {
    int i = blockIdx.x * 256 + threadIdx.x;
    if (i < n4) {
        float4 v = *(const float4*)(src + 4 * (size_t)i);
        short4v o;
        o.x = (short)f2bf(v.x); o.y = (short)f2bf(v.y);
        o.z = (short)f2bf(v.z); o.w = (short)f2bf(v.w);
        *(short4v*)(dst + 4 * (size_t)i) = o;
    }
}

// ---------------- K1: per-batch sum / sumsq ----------------
__global__ __launch_bounds__(256) void k_reduce(const float* __restrict__ x,
                                                float* __restrict__ sums) {
    int bx = blockIdx.x;
    int b = bx >> 5, slice = bx & 31;
    int t = threadIdx.x;
    const float4* xb = (const float4*)(x + (size_t)b * C_ * HW_);
    float s = 0.f, sq = 0.f;
    int base = slice * 8192 + t;
    #pragma unroll 4
    for (int r = 0; r < 32; ++r) {
        float4 v = xb[base + r * 256];
        s  += (v.x + v.y) + (v.z + v.w);
        sq += (v.x * v.x + v.y * v.y) + (v.z * v.z + v.w * v.w);
    }
    for (int off = 32; off; off >>= 1) {
        s  += __shfl_down(s, off);
        sq += __shfl_down(sq, off);
    }
    __shared__ float ls[4], lq[4];
    int wid = t >> 6;
    if ((t & 63) == 0) { ls[wid] = s; lq[wid] = sq; }
    __syncthreads();
    if (t == 0) {
        s  = (ls[0] + ls[1]) + (ls[2] + ls[3]);
        sq = (lq[0] + lq[1]) + (lq[2] + lq[3]);
        atomicAdd(&sums[2 * b], s);
        atomicAdd(&sums[2 * b + 1], sq);
    }
}

// ---------------- K2: finalize mu / rsqrt ----------------
__global__ void k_finalize(const float* __restrict__ sums, float* __restrict__ stat) {
    int b = threadIdx.x;
    if (b < B_) {
        float n = (float)((size_t)C_ * HW_);
        float mu = sums[2 * b] / n;
        float var = sums[2 * b + 1] / n - mu * mu;
        stat[2 * b] = mu;
        stat[2 * b + 1] = rsqrtf(var + EPS_);
    }
}

// ---------------- K3: norm + affine + LDS transpose + 2x2 pool ----------------
// block: 64 c-rows x 128 i (two h-rows). Writes xn f32 [c][i], xnb bf16 [i][c],
// xnpb bf16 [j][c]  (transposed layouts give k-contiguous MFMA B-fragments).
__global__ __launch_bounds__(256) void k_norm_tp(
        const float* __restrict__ x, const float* __restrict__ gamma,
        const float* __restrict__ beta, const float* __restrict__ stat,
        float* __restrict__ xn, ushort_t* __restrict__ xnb,
        ushort_t* __restrict__ xnpb) {
    __shared__ ushort_t T[128 * 80];   // [i][c] tile, row pitch 80 (160B, 16B-aligned)
    int t = threadIdx.x;
    int r  = blockIdx.x;               // h-pair 0..31
    int c0 = blockIdx.y * 64;
    int b  = blockIdx.z;
    int i0 = r * 128;

    float mu = stat[2 * b], rs = stat[2 * b + 1];
    int cl = t >> 2;
    float gv = gamma[c0 + cl] * rs;
    float bv = beta[c0 + cl] - mu * gv;
    const float* xrow = x  + ((size_t)(b * C_ + c0 + cl) * HW_ + i0);
    float*      xnrow = xn + ((size_t)(b * C_ + c0 + cl) * HW_ + i0);
    #pragma unroll
    for (int u = 0; u < 8; ++u) {
        int f4 = (t & 3) + 4 * u;
        float4 v = *(const float4*)(xrow + f4 * 4);
        v.x = v.x * gv + bv; v.y = v.y * gv + bv;
        v.z = v.z * gv + bv; v.w = v.w * gv + bv;
        *(float4*)(xnrow + f4 * 4) = v;
        int ib = f4 * 4;
        T[(ib + 0) * 80 + cl] = f2bf(v.x);
        T[(ib + 1) * 80 + cl] = f2bf(v.y);
        T[(ib + 2) * 80 + cl] = f2bf(v.z);
        T[(ib + 3) * 80 + cl] = f2bf(v.w);
    }
    __syncthreads();
    {   // xnb[i][c], coalesced via transpose
        int i = t >> 1, ch = t & 1;
        ushort_t* dst = xnb + ((size_t)(b * HW_ + i0 + i) * C_ + c0 + ch * 32);
        #pragma unroll
        for (int u = 0; u < 4; ++u) {
            bf16x8 vv = *(const bf16x8*)&T[i * 80 + ch * 32 + u * 8];
            *(bf16x8*)(dst + u * 8) = vv;
        }
    }
    {   // 2x2 pool -> xnpb[j][c]
        int w2 = t >> 3, c8 = (t & 7) * 8;
        bf16x8 p0 = *(const bf16x8*)&T[(2 * w2 + 0) * 80 + c8];
        bf16x8 p1 = *(const bf16x8*)&T[(2 * w2 + 1) * 80 + c8];
        bf16x8 p2 = *(const bf16x8*)&T[(64 + 2 * w2 + 0) * 80 + c8];
        bf16x8 p3 = *(const bf16x8*)&T[(64 + 2 * w2 + 1) * 80 + c8];
        bf16x8 res;
        #pragma unroll
        for (int e = 0; e < 8; ++e) {
            float s = bf2f((ushort_t)p0[e]) + bf2f((ushort_t)p1[e]) +
                      bf2f((ushort_t)p2[e]) + bf2f((ushort_t)p3[e]);
            res[e] = (short)f2bf(0.25f * s);
        }
        int j = r * 32 + w2;
        *(bf16x8*)&xnpb[((size_t)(b * JP_) + j) * C_ + c0 + c8] = res;
    }
}

// ---------------- K4: bf16 MFMA GEMM  Y[b] = W(Mx256) x X[b](256xN) ----------------
// X is [b][n][k] (k contiguous). No LDS: A-frags from L2-resident W, B-frags direct.
// MODE 0: Y bf16 natural [b][m][N]         (V)
// MODE 1: Y bf16 transposed [b][n][256]*scale  (Qt, Kt)
// MODE 2: Y fp32 natural + bias[m] + resid (proj out)
template <int MODE>
__global__ __launch_bounds__(256) void k_mm(
        const ushort_t* __restrict__ Wb, const ushort_t* __restrict__ Xb,
        void* __restrict__ Yp, int N, float scale,
        const float* __restrict__ bias, const float* __restrict__ resid) {
    int t = threadIdx.x;
    int w = t >> 6, l = t & 63;
    int il = l & 15, g = l >> 4;
    int n0 = blockIdx.x * 64, m0 = blockIdx.y * 64, b = blockIdx.z;
    int mw = m0 + 16 * w;

    const ushort_t* wp = Wb + (size_t)(mw + il) * C_ + 8 * g;
    bf16x8 A[8];
    #pragma unroll
    for (int ks = 0; ks < 8; ++ks) A[ks] = *(const bf16x8*)(wp + 32 * ks);

    const ushort_t* xp = Xb + ((size_t)b * N + n0 + il) * C_ + 8 * g;
    f32x4 acc0 = {0,0,0,0}, acc1 = {0,0,0,0}, acc2 = {0,0,0,0}, acc3 = {0,0,0,0};
    #pragma unroll
    for (int ks = 0; ks < 8; ++ks) {
        bf16x8 b0 = *(const bf16x8*)(xp + 32 * ks);
        bf16x8 b1 = *(const bf16x8*)(xp + (size_t)16 * C_ + 32 * ks);
        bf16x8 b2 = *(const bf16x8*)(xp + (size_t)32 * C_ + 32 * ks);
        bf16x8 b3 = *(const bf16x8*)(xp + (size_t)48 * C_ + 32 * ks);
        acc0 = __builtin_amdgcn_mfma_f32_16x16x32_bf16(A[ks], b0, acc0, 0, 0, 0);
        acc1 = __builtin_amdgcn_mfma_f32_16x16x32_bf16(A[ks], b1, acc1, 0, 0, 0);
        acc2 = __builtin_amdgcn_mfma_f32_16x16x32_bf16(A[ks], b2, acc2, 0, 0, 0);
        acc3 = __builtin_amdgcn_mfma_f32_16x16x32_bf16(A[ks], b3, acc3, 0, 0, 0);
    }
    // D-frag: col n = l&15 (+16*nt), rows m = mw + 4*g + r   [m89 layout]
    f32x4 accs[4] = {acc0, acc1, acc2, acc3};
    #pragma unroll
    for (int nt = 0; nt < 4; ++nt) {
        int n = n0 + 16 * nt + il;
        f32x4 a = accs[nt];
        if (MODE == 0) {
            ushort_t* Y = (ushort_t*)Yp;
            size_t base = ((size_t)(b * C_) + mw + 4 * g) * N + n;
            Y[base]             = f2bf(a.x);
            Y[base + (size_t)N] = f2bf(a.y);
            Y[base + (size_t)2 * N] = f2bf(a.z);
            Y[base + (size_t)3 * N] = f2bf(a.w);
        } else if (MODE == 1) {
            ushort_t* Y = (ushort_t*)Yp;
            short4v pv;
            pv.x = (short)f2bf(a.x * scale); pv.y = (short)f2bf(a.y * scale);
            pv.z = (short)f2bf(a.z * scale); pv.w = (short)f2bf(a.w * scale);
            *(short4v*)&Y[((size_t)b * N + n) * C_ + mw + 4 * g] = pv;
        } else {
            float* Y = (float*)Yp;
            #pragma unroll
            for (int rr = 0; rr < 4; ++rr) {
                int m = mw + 4 * g + rr;
                size_t yi = ((size_t)(b * C_) + m) * N + n;
                float v = (rr == 0 ? a.x : rr == 1 ? a.y : rr == 2 ? a.z : a.w);
                Y[yi] = v + bias[m] + resid[yi];
            }
        }
    }
}

// ---------------- K5: MFMA flash attention ----------------
// Per block: one (b,h), 64 queries (4 waves x 16), loop 16 tiles of 64 j.
// S^T = mfma(A=Kt, B=Qt)  -> per-lane softmax (lane owns one query column)
// O   = mfma(A=V,  B=P)   -> O[c][i], stored transposed to AOt[b][i][c].
__global__ __launch_bounds__(256) void k_attn(
        const ushort_t* __restrict__ Qt, const ushort_t* __restrict__ Kt,
        const ushort_t* __restrict__ Vb, ushort_t* __restrict__ AOt) {
    __shared__ ushort_t KV[2][8192];   // per buf: Kt[64j][64c] @0, V[64c][64j] @4096
    __shared__ ushort_t PL[4][1024];   // per-wave P[16i][64j] bf16
    int t = threadIdx.x;
    int w = t >> 6, l = t & 63;
    int il = l & 15, g = l >> 4;
    int b = blockIdx.z, h = blockIdx.y;
    int i0 = blockIdx.x * 64, c0 = h * 64;

    // persistent Q B-fragments (scale 1/16 pre-folded in Qt)
    const ushort_t* qp = Qt + ((size_t)(b * HW_ + i0 + 16 * w + il) * C_ + c0 + 8 * g);
    bf16x8 qf0 = *(const bf16x8*)qp;
    bf16x8 qf1 = *(const bf16x8*)(qp + 32);

    // staging: each wave covers rows 16w..16w+15 (2 groups of 8) for K and V
    int srow = l >> 3, sslot = l & 7;
    int swz_w = (srow & 7) << 3;                       // row&7 == srow for both groups
    const ushort_t* kg = Kt + ((size_t)(b * JP_) + 16 * w + srow) * C_ + c0 + 8 * sslot;
    const ushort_t* vg = Vb + ((size_t)(b * C_) + c0 + 16 * w + srow) * JP_ + 8 * sslot;
    int wr0 = (16 * w + srow) * 64 + ((8 * sslot) ^ swz_w);
    int wr1 = wr0 + 8 * 64;

    int rswz = (l & 7) << 3;                           // read swizzle: (row&7)<<3, row=16mt+il
    int e0 = (8 * g) ^ rswz;                           // kt=0 column group
    int e1 = (32 + 8 * g) ^ rswz;                      // kt=1 column group

    f32x4 o0 = {0,0,0,0}, o1 = {0,0,0,0}, o2 = {0,0,0,0}, o3 = {0,0,0,0};
    float mold = -3.0e38f, lsum = 0.f;

    // prologue: stage tile 0
    bf16x8 kr0 = *(const bf16x8*)(kg);
    bf16x8 kr1 = *(const bf16x8*)(kg + (size_t)8 * C_);
    bf16x8 vr0 = *(const bf16x8*)(vg);
    bf16x8 vr1 = *(const bf16x8*)(vg + (size_t)8 * JP_);
    *(bf16x8*)&KV[0][wr0] = kr0;        *(bf16x8*)&KV[0][wr1] = kr1;
    *(bf16x8*)&KV[0][4096 + wr0] = vr0; *(bf16x8*)&KV[0][4096 + wr1] = vr1;

    for (int tb = 0; tb < 16; ++tb) {
        int cur = tb & 1;
        if (tb < 15) {                                  // issue next-tile loads early
            int jb = (tb + 1) * 64;
            kr0 = *(const bf16x8*)(kg + (size_t)jb * C_);
            kr1 = *(const bf16x8*)(kg + (size_t)(jb + 8) * C_);
            vr0 = *(const bf16x8*)(vg + jb);
            vr1 = *(const bf16x8*)(vg + (size_t)8 * JP_ + jb);
        }
        __syncthreads();                                // tile tb visible to all waves
        const ushort_t* kb = KV[cur];
        const ushort_t* vt = KV[cur] + 4096;

        // ---- S^T = Kt x Q : 4 row-tiles x 2 k-steps ----
        f32x4 z = {0,0,0,0};
        bf16x8 ka, kc;
        f32x4 s0, s1, s2, s3;
        ka = *(const bf16x8*)&kb[il * 64 + e0];
        kc = *(const bf16x8*)&kb[il * 64 + e1];
        s0 = __builtin_amdgcn_mfma_f32_16x16x32_bf16(ka, qf0, z, 0, 0, 0);
        s0 = __builtin_amdgcn_mfma_f32_16x16x32_bf16(kc, qf1, s0, 0, 0, 0);
        ka = *(const bf16x8*)&kb[1024 + il * 64 + e0];
        kc = *(const bf16x8*)&kb[1024 + il * 64 + e1];
        s1 = __builtin_amdgcn_mfma_f32_16x16x32_bf16(ka, qf0, z, 0, 0, 0);
        s1 = __builtin_amdgcn_mfma_f32_16x16x32_bf16(kc, qf1, s1, 0, 0, 0);
        ka = *(const bf16x8*)&kb[2048 + il * 64 + e0];
        kc = *(const bf16x8*)&kb[2048 + il * 64 + e1];
        s2 = __builtin_amdgcn_mfma_f32_16x16x32_bf16(ka, qf0, z, 0, 0, 0);
        s2 = __builtin_amdgcn_mfma_f32_16x16x32_bf16(kc, qf1, s2, 0, 0, 0);
        ka = *(const bf16x8*)&kb[3072 + il * 64 + e0];
        kc = *(const bf16x8*)&kb[3072 + il * 64 + e1];
        s3 = __builtin_amdgcn_mfma_f32_16x16x32_bf16(ka, qf0, z, 0, 0, 0);
        s3 = __builtin_amdgcn_mfma_f32_16x16x32_bf16(kc, qf1, s3, 0, 0, 0);

        // ---- per-lane online softmax (lane owns query column il) ----
        float mx = fmaxf(fmaxf(fmaxf(s0.x, s0.y), fmaxf(s0.z, s0.w)),
                         fmaxf(fmaxf(s1.x, s1.y), fmaxf(s1.z, s1.w)));
        mx = fmaxf(mx, fmaxf(fmaxf(fmaxf(s2.x, s2.y), fmaxf(s2.z, s2.w)),
                             fmaxf(fmaxf(s3.x, s3.y), fmaxf(s3.z, s3.w))));
        mx = fmaxf(mx, __shfl_xor(mx, 16));
        mx = fmaxf(mx, __shfl_xor(mx, 32));
        float mnew = fmaxf(mold, mx);
        float corr = __expf(mold - mnew);
        mold = mnew;
        s0.x = __expf(s0.x - mnew); s0.y = __expf(s0.y - mnew);
        s0.z = __expf(s0.z - mnew); s0.w = __expf(s0.w - mnew);
        s1.x = __expf(s1.x - mnew); s1.y = __expf(s1.y - mnew);
        s1.z = __expf(s1.z - mnew); s1.w = __expf(s1.w - mnew);
        s2.x = __expf(s2.x - mnew); s2.y = __expf(s2.y - mnew);
        s2.z = __expf(s2.z - mnew); s2.w = __expf(s2.w - mnew);
        s3.x = __expf(s3.x - mnew); s3.y = __expf(s3.y - mnew);
        s3.z = __expf(s3.z - mnew); s3.w = __expf(s3.w - mnew);
        lsum = lsum * corr +
               (((s0.x + s0.y) + (s0.z + s0.w)) + ((s1.x + s1.y) + (s1.z + s1.w))) +
               (((s2.x + s2.y) + (s2.z + s2.w)) + ((s3.x + s3.y) + (s3.z + s3.w)));
        o0 *= corr; o1 *= corr; o2 *= corr; o3 *= corr;

        // ---- pack P -> wave-private LDS [i][j] (same XOR swizzle) ----
        ushort_t* pl = PL[w];
        int prow = il * 64;
        short4v pv;
        pv.x = (short)f2bf(s0.x); pv.y = (short)f2bf(s0.y);
        pv.z = (short)f2bf(s0.z); pv.w = (short)f2bf(s0.w);
        *(short4v*)&pl[prow + ((4 * g) ^ rswz)] = pv;
        pv.x = (short)f2bf(s1.x); pv.y = (short)f2bf(s1.y);
        pv.z = (short)f2bf(s1.z); pv.w = (short)f2bf(s1.w);
        *(short4v*)&pl[prow + ((16 + 4 * g) ^ rswz)] = pv;
        pv.x = (short)f2bf(s2.x); pv.y = (short)f2bf(s2.y);
        pv.z = (short)f2bf(s2.z); pv.w = (short)f2bf(s2.w);
        *(short4v*)&pl[prow + ((32 + 4 * g) ^ rswz)] = pv;
        pv.x = (short)f2bf(s3.x); pv.y = (short)f2bf(s3.y);
        pv.z = (short)f2bf(s3.z); pv.w = (short)f2bf(s3.w);
        *(short4v*)&pl[prow + ((48 + 4 * g) ^ rswz)] = pv;

        // ---- O += V x P ----
        bf16x8 pb0 = *(const bf16x8*)&pl[prow + e0];
        bf16x8 pb1 = *(const bf16x8*)&pl[prow + e1];
        bf16x8 va, vc;
        va = *(const bf16x8*)&vt[il * 64 + e0];
        vc = *(const bf16x8*)&vt[il * 64 + e1];
        o0 = __builtin_amdgcn_mfma_f32_16x16x32_bf16(va, pb0, o0, 0, 0, 0);
        o0 = __builtin_amdgcn_mfma_f32_16x16x32_bf16(vc, pb1, o0, 0, 0, 0);
        va = *(const bf16x8*)&vt[1024 + il * 64 + e0];
        vc = *(const bf16x8*)&vt[1024 + il * 64 + e1];
        o1 = __builtin_amdgcn_mfma_f32_16x16x32_bf16(va, pb0, o1, 0, 0, 0);
        o1 = __builtin_amdgcn_mfma_f32_16x16x32_bf16(vc, pb1, o1, 0, 0, 0);
        va = *(const bf16x8*)&vt[2048 + il * 64 + e0];
        vc = *(const bf16x8*)&vt[2048 + il * 64 + e1];
        o2 = __builtin_amdgcn_mfma_f32_16x16x32_bf16(va, pb0, o2, 0, 0, 0);
        o2 = __builtin_amdgcn_mfma_f32_16x16x32_bf16(vc, pb1, o2, 0, 0, 0);
        va = *(const bf16x8*)&vt[3072 + il * 64 + e0];
        vc = *(const bf16x8*)&vt[3072 + il * 64 + e1];
        o3 = __builtin_amdgcn_mfma_f32_16x16x32_bf16(va, pb0, o3, 0, 0, 0);
        o3 = __builtin_amdgcn_mfma_f32_16x16x32_bf16(vc, pb1, o3, 0, 0, 0);

        // ---- write next tile into the other buffer (safe: one barrier/iter) ----
        if (tb < 15) {
            int nxt = cur ^ 1;
            *(bf16x8*)&KV[nxt][wr0] = kr0;        *(bf16x8*)&KV[nxt][wr1] = kr1;
            *(bf16x8*)&KV[nxt][4096 + wr0] = vr0; *(bf16x8*)&KV[nxt][4096 + wr1] = vr1;
        }
    }

    lsum += __shfl_xor(lsum, 16);
    lsum += __shfl_xor(lsum, 32);
    float inv = 1.f / lsum;
    // O-frag: col i = il, rows c = 16*mt + 4*g + r  -> AOt[b][i][c] packed 4-wide
    ushort_t* ao = AOt + ((size_t)(b * HW_ + i0 + 16 * w + il) * C_ + c0 + 4 * g);
    short4v ov;
    ov.x = (short)f2bf(o0.x * inv); ov.y = (short)f2bf(o0.y * inv);
    ov.z = (short)f2bf(o0.z * inv); ov.w = (short)f2bf(o0.w * inv);
    *(short4v*)(ao +  0) = ov;
    ov.x = (short)f2bf(o1.x * inv); ov.y = (short)f2bf(o1.y * inv);
    ov.z = (short)f2bf(o1.z * inv); ov.w = (short)f2bf(o1.w * inv);
    *(short4v*)(ao + 16) = ov;
    ov.x = (short)f2bf(o2.x * inv); ov.y = (short)f2bf(o2.y * inv);
    ov.z = (short)f2bf(o2.z * inv); ov.w = (short)f2bf(o2.w * inv);
    *(short4v*)(ao + 32) = ov;
    ov.x = (short)f2bf(o3.x * inv); ov.y = (short)f2bf(o3.y * inv);
    ov.z = (short)f2bf(o3.z * inv); ov.w = (short)f2bf(o3.w * inv);
    *(short4v*)(ao + 48) = ov;
}

// ---------------- launch ----------------
extern "C" void kernel_launch(void* const* d_in, const int* in_sizes, int n_in,
                              void* d_out, int out_size, void* d_ws, size_t ws_size,
                              hipStream_t stream) {
    const float* x      = (const float*)d_in[0];
    const float* gamma  = (const float*)d_in[1];
    const float* beta   = (const float*)d_in[2];
    const float* w_qkv  = (const float*)d_in[3];
    const float* w_proj = (const float*)d_in[4];
    const float* b_proj = (const float*)d_in[5];
    float* out = (float*)d_out;
    char* ws = (char*)d_ws;

    float*    xn   = (float*)(ws + OFF_XN);
    ushort_t* xnb  = (ushort_t*)(ws + OFF_XNB);
    ushort_t* aot  = (ushort_t*)(ws + OFF_AOT);
    ushort_t* xnpb = (ushort_t*)(ws + OFF_XNPB);
    ushort_t* qt   = (ushort_t*)(ws + OFF_QT);
    ushort_t* kt   = (ushort_t*)(ws + OFF_KT);
    ushort_t* vb   = (ushort_t*)(ws + OFF_VB);
    ushort_t* wqb  = (ushort_t*)(ws + OFF_WQB);
    ushort_t* wpb  = (ushort_t*)(ws + OFF_WPB);
    float*    sums = (float*)(ws + OFF_SUM);
    float*    stat = (float*)(ws + OFF_STAT);

    hipMemsetAsync(sums, 0, 2 * B_ * sizeof(float), stream);
    k_cvt<<<192, 256, 0, stream>>>(w_qkv, wqb, 3 * C_ * C_ / 4);
    k_cvt<<<64, 256, 0, stream>>>(w_proj, wpb, C_ * C_ / 4);
    k_reduce<<<256, 256, 0, stream>>>(x, sums);
    k_finalize<<<1, 64, 0, stream>>>(sums, stat);
    k_norm_tp<<<dim3(32, 4, 8), 256, 0, stream>>>(x, gamma, beta, stat, xn, xnb, xnpb);
    // Qt = (W_q @ xn)^T * (C^-0.5)            M=256, N=4096
    k_mm<1><<<dim3(64, 4, 8), 256, 0, stream>>>(wqb, xnb, qt, HW_, 0.0625f,
                                                nullptr, nullptr);
    // Kt = (W_k @ pool(xn))^T                 M=256, N=1024
    k_mm<1><<<dim3(16, 4, 8), 256, 0, stream>>>(wqb + (size_t)C_ * C_, xnpb, kt, JP_,
                                                1.0f, nullptr, nullptr);
    // V  = W_v @ pool(xn)                     M=256, N=1024
    k_mm<0><<<dim3(16, 4, 8), 256, 0, stream>>>(wqb + (size_t)2 * C_ * C_, xnpb, vb,
                                                JP_, 1.0f, nullptr, nullptr);
    // attention -> AOt (aliases dead xnb)
    k_attn<<<dim3(64, 4, 8), 256, 0, stream>>>(qt, kt, vb, aot);
    // out = W_proj @ attn_out + b_proj + xn
    k_mm<2><<<dim3(64, 4, 8), 256, 0, stream>>>(wpb, aot, out, HW_, 1.0f,
                                                b_proj, xn);
}

// Round 4
// 249.278 us; speedup vs baseline: 1.1278x; 1.1278x over previous
//
#include <hip/hip_runtime.h>
#include <hip/hip_bf16.h>
#include <math.h>

#define B_ 8
#define C_ 256
#define HW_ 4096
#define JP_ 1024
#define EPS_ 1e-5f

typedef __attribute__((ext_vector_type(8))) short bf16x8;   // 8 bf16 (4 VGPR) MFMA frag
typedef __attribute__((ext_vector_type(4))) short short4v;  // 8B packed bf16 store
typedef __attribute__((ext_vector_type(4))) float f32x4;    // MFMA accumulator
typedef unsigned short ushort_t;
typedef unsigned int uint_t;

__device__ __forceinline__ ushort_t f2bf(float f) {
    uint_t u = __float_as_uint(f);
    u += 0x7fffu + ((u >> 16) & 1u);       // round-nearest-even
    return (ushort_t)(u >> 16);
}
__device__ __forceinline__ float bf2f(ushort_t h) {
    return __uint_as_float(((uint_t)h) << 16);
}
__device__ __forceinline__ float exp2fast(float x) {
#if __has_builtin(__builtin_amdgcn_exp2f)
    return __builtin_amdgcn_exp2f(x);      // v_exp_f32: D = 2^x
#else
    return __expf(x * 0.69314718056f);
#endif
}
// pack 2 floats -> 2 bf16 in one u32 (compiler emits v_cvt_pk_bf16_f32)
__device__ __forceinline__ uint_t pk2bf(float a, float b) {
    __hip_bfloat162 h = __float22bfloat162_rn(float2{a, b});
    return *reinterpret_cast<uint_t*>(&h);
}

// ---------------- workspace layout (bytes) ----------------
static const size_t OFF_XN   = 0;            // xn   f32  [b][c][i]  32 MB
static const size_t OFF_XNB  = 33554432;     // xnb  bf16 [b][i][c]  16 MB
static const size_t OFF_AOT  = OFF_XNB;      // AOt aliases xnb (dead after q-GEMM)
static const size_t OFF_XNPB = 50331648;     // xnpb bf16 [b][j][c]   4 MB
static const size_t OFF_QT   = 54525952;     // Qt   bf16 [b][i][c]  16 MB (pre-scaled)
static const size_t OFF_KT   = 71303168;     // Kt   bf16 [b][j][c]   4 MB
static const size_t OFF_VB   = 75497472;     // V    bf16 [b][c][j]   4 MB
static const size_t OFF_WQB  = 79691776;
static const size_t OFF_WPB  = 80084992;
static const size_t OFF_SUM  = 80216064;
static const size_t OFF_STAT = 80216128;

// ---------------- K0: fp32 -> bf16 weight convert ----------------
__global__ __launch_bounds__(256) void k_cvt(const float* __restrict__ src,
                                             ushort_t* __restrict__ dst, int n4) {
    int i = blockIdx.x * 256 + threadIdx.x;
    if (i < n4) {
        float4 v = *(const float4*)(src + 4 * (size_t)i);
        short4v o;
        o.x = (short)f2bf(v.x); o.y = (short)f2bf(v.y);
        o.z = (short)f2bf(v.z); o.w = (short)f2bf(v.w);
        *(short4v*)(dst + 4 * (size_t)i) = o;
    }
}

// ---------------- K1: per-batch sum / sumsq ----------------
__global__ __launch_bounds__(256) void k_reduce(const float* __restrict__ x,
                                                float* __restrict__ sums) {
    int bx = blockIdx.x;
    int b = bx >> 5, slice = bx & 31;
    int t = threadIdx.x;
    const float4* xb = (const float4*)(x + (size_t)b * C_ * HW_);
    float s = 0.f, sq = 0.f;
    int base = slice * 8192 + t;
    #pragma unroll 4
    for (int r = 0; r < 32; ++r) {
        float4 v = xb[base + r * 256];
        s  += (v.x + v.y) + (v.z + v.w);
        sq += (v.x * v.x + v.y * v.y) + (v.z * v.z + v.w * v.w);
    }
    for (int off = 32; off; off >>= 1) {
        s  += __shfl_down(s, off);
        sq += __shfl_down(sq, off);
    }
    __shared__ float ls[4], lq[4];
    int wid = t >> 6;
    if ((t & 63) == 0) { ls[wid] = s; lq[wid] = sq; }
    __syncthreads();
    if (t == 0) {
        s  = (ls[0] + ls[1]) + (ls[2] + ls[3]);
        sq = (lq[0] + lq[1]) + (lq[2] + lq[3]);
        atomicAdd(&sums[2 * b], s);
        atomicAdd(&sums[2 * b + 1], sq);
    }
}

// ---------------- K2: finalize mu / rsqrt ----------------
__global__ void k_finalize(const float* __restrict__ sums, float* __restrict__ stat) {
    int b = threadIdx.x;
    if (b < B_) {
        float n = (float)((size_t)C_ * HW_);
        float mu = sums[2 * b] / n;
        float var = sums[2 * b + 1] / n - mu * mu;
        stat[2 * b] = mu;
        stat[2 * b + 1] = rsqrtf(var + EPS_);
    }
}

// ---------------- K3: norm + affine + LDS transpose + 2x2 pool ----------------
// pitch 88 (176B = 44 dwords): write-path bank stride 176%128B -> <=2-way (free)
__global__ __launch_bounds__(256) void k_norm_tp(
        const float* __restrict__ x, const float* __restrict__ gamma,
        const float* __restrict__ beta, const float* __restrict__ stat,
        float* __restrict__ xn, ushort_t* __restrict__ xnb,
        ushort_t* __restrict__ xnpb) {
    __shared__ ushort_t T[128 * 88];
    int t = threadIdx.x;
    int r  = blockIdx.x;               // h-pair 0..31
    int c0 = blockIdx.y * 64;
    int b  = blockIdx.z;
    int i0 = r * 128;

    float mu = stat[2 * b], rs = stat[2 * b + 1];
    int cl = t >> 2;
    float gv = gamma[c0 + cl] * rs;
    float bv = beta[c0 + cl] - mu * gv;
    const float* xrow = x  + ((size_t)(b * C_ + c0 + cl) * HW_ + i0);
    float*      xnrow = xn + ((size_t)(b * C_ + c0 + cl) * HW_ + i0);
    #pragma unroll
    for (int u = 0; u < 8; ++u) {
        int f4 = (t & 3) + 4 * u;
        float4 v = *(const float4*)(xrow + f4 * 4);
        v.x = v.x * gv + bv; v.y = v.y * gv + bv;
        v.z = v.z * gv + bv; v.w = v.w * gv + bv;
        *(float4*)(xnrow + f4 * 4) = v;
        int ib = f4 * 4;
        T[(ib + 0) * 88 + cl] = f2bf(v.x);
        T[(ib + 1) * 88 + cl] = f2bf(v.y);
        T[(ib + 2) * 88 + cl] = f2bf(v.z);
        T[(ib + 3) * 88 + cl] = f2bf(v.w);
    }
    __syncthreads();
    {   // xnb[i][c], coalesced via transpose
        int i = t >> 1, ch = t & 1;
        ushort_t* dst = xnb + ((size_t)(b * HW_ + i0 + i) * C_ + c0 + ch * 32);
        #pragma unroll
        for (int u = 0; u < 4; ++u) {
            bf16x8 vv = *(const bf16x8*)&T[i * 88 + ch * 32 + u * 8];
            *(bf16x8*)(dst + u * 8) = vv;
        }
    }
    {   // 2x2 pool -> xnpb[j][c]
        int w2 = t >> 3, c8 = (t & 7) * 8;
        bf16x8 p0 = *(const bf16x8*)&T[(2 * w2 + 0) * 88 + c8];
        bf16x8 p1 = *(const bf16x8*)&T[(2 * w2 + 1) * 88 + c8];
        bf16x8 p2 = *(const bf16x8*)&T[(64 + 2 * w2 + 0) * 88 + c8];
        bf16x8 p3 = *(const bf16x8*)&T[(64 + 2 * w2 + 1) * 88 + c8];
        bf16x8 res;
        #pragma unroll
        for (int e = 0; e < 8; ++e) {
            float s = bf2f((ushort_t)p0[e]) + bf2f((ushort_t)p1[e]) +
                      bf2f((ushort_t)p2[e]) + bf2f((ushort_t)p3[e]);
            res[e] = (short)f2bf(0.25f * s);
        }
        int j = r * 32 + w2;
        *(bf16x8*)&xnpb[((size_t)(b * JP_) + j) * C_ + c0 + c8] = res;
    }
}

// ---------------- K4: bf16 MFMA GEMM, 4 m-subtiles/wave (16 MFMA : 4 loads) -------
// X [b][n][k] k-contiguous. Block: m 256 x n 64, 4 waves.
// MODE 0: Y bf16 [b][m][N];  MODE 1: Y bf16 [b][n][256]*scale;  MODE 2: f32 +bias+resid
template <int MODE>
__global__ __launch_bounds__(256, 2) void k_mm(
        const ushort_t* __restrict__ Wb, const ushort_t* __restrict__ Xb,
        void* __restrict__ Yp, int N, float scale, size_t strideY,
        const float* __restrict__ bias, const float* __restrict__ resid) {
    int t = threadIdx.x;
    int w = t >> 6, l = t & 63;
    int il = l & 15, g = l >> 4;
    int n0 = blockIdx.x * 64, m0 = blockIdx.y * 256, b = blockIdx.z;

    bf16x8 A[4][8];
    #pragma unroll
    for (int ms = 0; ms < 4; ++ms) {
        const ushort_t* wp = Wb + (size_t)(m0 + 64 * ms + 16 * w + il) * C_ + 8 * g;
        #pragma unroll
        for (int ks = 0; ks < 8; ++ks) A[ms][ks] = *(const bf16x8*)(wp + 32 * ks);
    }

    const ushort_t* xp = Xb + ((size_t)b * N + n0 + il) * C_ + 8 * g;
    f32x4 acc[4][4] = {};   // [ms][nt]
    #pragma unroll
    for (int ks = 0; ks < 8; ++ks) {
        bf16x8 bb[4];
        #pragma unroll
        for (int nt = 0; nt < 4; ++nt)
            bb[nt] = *(const bf16x8*)(xp + (size_t)16 * nt * C_ + 32 * ks);
        #pragma unroll
        for (int ms = 0; ms < 4; ++ms)
            #pragma unroll
            for (int nt = 0; nt < 4; ++nt)
                acc[ms][nt] = __builtin_amdgcn_mfma_f32_16x16x32_bf16(
                    A[ms][ks], bb[nt], acc[ms][nt], 0, 0, 0);
    }
    #pragma unroll
    for (int ms = 0; ms < 4; ++ms) {
        int mwg = m0 + 64 * ms + 16 * w + 4 * g;
        #pragma unroll
        for (int nt = 0; nt < 4; ++nt) {
            int n = n0 + 16 * nt + il;
            f32x4 a = acc[ms][nt];
            if (MODE == 0) {
                ushort_t* Y = (ushort_t*)Yp;
                size_t base = (size_t)b * strideY + (size_t)mwg * N + n;
                Y[base]                 = f2bf(a.x);
                Y[base + (size_t)N]     = f2bf(a.y);
                Y[base + (size_t)2 * N] = f2bf(a.z);
                Y[base + (size_t)3 * N] = f2bf(a.w);
            } else if (MODE == 1) {
                ushort_t* Y = (ushort_t*)Yp;
                short4v pv;
                pv.x = (short)f2bf(a.x * scale); pv.y = (short)f2bf(a.y * scale);
                pv.z = (short)f2bf(a.z * scale); pv.w = (short)f2bf(a.w * scale);
                *(short4v*)&Y[((size_t)b * N + n) * C_ + mwg] = pv;
            } else {
                float* Y = (float*)Yp;
                #pragma unroll
                for (int rr = 0; rr < 4; ++rr) {
                    int m = mwg + rr;
                    size_t yi = (size_t)b * strideY + (size_t)m * N + n;
                    float v = (rr == 0 ? a.x : rr == 1 ? a.y : rr == 2 ? a.z : a.w);
                    Y[yi] = v + bias[m] + resid[yi];
                }
            }
        }
    }
}

// ---------------- K5: MFMA flash attention, 64 queries/wave ----------------
// Block: 256 queries (4 waves x 64), one (b,h); 16 tiles of 64 j.
// S^T = mfma(A=K, B=Q) -> per-lane softmax (4 query cols/lane, log2 domain,
// defer-max THR=8). O = mfma(A=V, B=P). LDS: KV dbuf 32KB + per-wave P 32KB.
__global__ __launch_bounds__(256, 2) void k_attn(
        const ushort_t* __restrict__ Qt, const ushort_t* __restrict__ Kt,
        const ushort_t* __restrict__ Vb, ushort_t* __restrict__ AOt) {
    __shared__ ushort_t KV[2][8192];   // per buf: K[64j][64c] @0, V[64c][64j] @4096
    __shared__ ushort_t PL[4][4096];   // per-wave P[64 i][64 j]
    int t = threadIdx.x;
    int w = t >> 6, l = t & 63;
    int il = l & 15, g = l >> 4;
    int b = blockIdx.z, h = blockIdx.y;
    int i0 = blockIdx.x * 256, c0 = h * 64;
    int iw = i0 + 64 * w;

    // persistent Q B-frags (Qt pre-scaled by C^-0.5 * log2(e))
    bf16x8 qf[4][2];
    {
        const ushort_t* qp = Qt + ((size_t)(b * HW_ + iw + il) * C_ + c0 + 8 * g);
        #pragma unroll
        for (int it = 0; it < 4; ++it) {
            qf[it][0] = *(const bf16x8*)(qp + (size_t)16 * it * C_);
            qf[it][1] = *(const bf16x8*)(qp + (size_t)16 * it * C_ + 32);
        }
    }

    // staging: wave covers rows 16w..16w+15 (2 groups of 8) for K and V
    int srow = l >> 3, sslot = l & 7;
    const ushort_t* kg = Kt + ((size_t)(b * JP_) + 16 * w + srow) * C_ + c0 + 8 * sslot;
    const ushort_t* vg = Vb + ((size_t)(b * C_) + c0 + 16 * w + srow) * JP_ + 8 * sslot;
    int wr0 = (16 * w + srow) * 64 + ((8 * sslot) ^ ((srow & 7) << 3));
    int wr1 = wr0 + 8 * 64;

    int rswz = (il & 7) << 3;
    int e0 = (8 * g) ^ rswz;
    int e1 = (32 + 8 * g) ^ rswz;

    f32x4 o[4][4] = {};                 // [ct][it]
    float mold[4], lsum[4];
    #pragma unroll
    for (int it = 0; it < 4; ++it) { mold[it] = -3.0e38f; lsum[it] = 0.f; }

    // prologue: stage tile 0
    bf16x8 kr0 = *(const bf16x8*)(kg);
    bf16x8 kr1 = *(const bf16x8*)(kg + (size_t)8 * C_);
    bf16x8 vr0 = *(const bf16x8*)(vg);
    bf16x8 vr1 = *(const bf16x8*)(vg + (size_t)8 * JP_);
    *(bf16x8*)&KV[0][wr0] = kr0;        *(bf16x8*)&KV[0][wr1] = kr1;
    *(bf16x8*)&KV[0][4096 + wr0] = vr0; *(bf16x8*)&KV[0][4096 + wr1] = vr1;

    ushort_t* pl = PL[w];

    for (int tb = 0; tb < 16; ++tb) {
        int cur = tb & 1;
        if (tb < 15) {                  // issue next-tile global loads early
            int jb = (tb + 1) * 64;
            kr0 = *(const bf16x8*)(kg + (size_t)jb * C_);
            kr1 = *(const bf16x8*)(kg + (size_t)(jb + 8) * C_);
            vr0 = *(const bf16x8*)(vg + jb);
            vr1 = *(const bf16x8*)(vg + (size_t)8 * JP_ + jb);
        }
        __syncthreads();
        const ushort_t* kb = KV[cur];
        const ushort_t* vt = KV[cur] + 4096;

        // ---- S^T[64j][64i] = K x Q ----
        f32x4 s[4][4];                  // [jt][it]
        #pragma unroll
        for (int jt = 0; jt < 4; ++jt) {
            bf16x8 ka0 = *(const bf16x8*)&kb[(16 * jt + il) * 64 + e0];
            bf16x8 ka1 = *(const bf16x8*)&kb[(16 * jt + il) * 64 + e1];
            #pragma unroll
            for (int it = 0; it < 4; ++it) {
                f32x4 z = {0.f, 0.f, 0.f, 0.f};
                s[jt][it] = __builtin_amdgcn_mfma_f32_16x16x32_bf16(ka0, qf[it][0], z, 0, 0, 0);
                s[jt][it] = __builtin_amdgcn_mfma_f32_16x16x32_bf16(ka1, qf[it][1], s[jt][it], 0, 0, 0);
            }
        }

        // write next tile into the other buffer (overlaps softmax VALU)
        if (tb < 15) {
            int nxt = cur ^ 1;
            *(bf16x8*)&KV[nxt][wr0] = kr0;        *(bf16x8*)&KV[nxt][wr1] = kr1;
            *(bf16x8*)&KV[nxt][4096 + wr0] = vr0; *(bf16x8*)&KV[nxt][4096 + wr1] = vr1;
        }

        // ---- per-lane online softmax (log2 domain), defer-max THR=8 ----
        float mxl[4];
        #pragma unroll
        for (int it = 0; it < 4; ++it) {
            float m01 = fmaxf(fmaxf(s[0][it].x, s[0][it].y), fmaxf(s[0][it].z, s[0][it].w));
            m01 = fmaxf(m01, fmaxf(fmaxf(s[1][it].x, s[1][it].y), fmaxf(s[1][it].z, s[1][it].w)));
            float m23 = fmaxf(fmaxf(s[2][it].x, s[2][it].y), fmaxf(s[2][it].z, s[2][it].w));
            m23 = fmaxf(m23, fmaxf(fmaxf(s[3][it].x, s[3][it].y), fmaxf(s[3][it].z, s[3][it].w)));
            mxl[it] = fmaxf(m01, m23);
        }
        float dmax = fmaxf(fmaxf(mxl[0] - mold[0], mxl[1] - mold[1]),
                           fmaxf(mxl[2] - mold[2], mxl[3] - mold[3]));
        if (!__all(dmax <= 8.0f)) {     // wave-uniform rescale branch
            #pragma unroll
            for (int it = 0; it < 4; ++it) {
                float mg = fmaxf(mxl[it], __shfl_xor(mxl[it], 16));
                mg = fmaxf(mg, __shfl_xor(mg, 32));
                float mn = fmaxf(mold[it], mg);
                float corr = exp2fast(mold[it] - mn);
                mold[it] = mn;
                lsum[it] *= corr;
                o[0][it] *= corr; o[1][it] *= corr; o[2][it] *= corr; o[3][it] *= corr;
            }
        }
        #pragma unroll
        for (int it = 0; it < 4; ++it) {
            float m = mold[it];
            float acc = 0.f;
            #pragma unroll
            for (int jt = 0; jt < 4; ++jt) {
                float p0 = exp2fast(s[jt][it].x - m);
                float p1 = exp2fast(s[jt][it].y - m);
                float p2 = exp2fast(s[jt][it].z - m);
                float p3 = exp2fast(s[jt][it].w - m);
                acc += (p0 + p1) + (p2 + p3);
                uint_t lo = pk2bf(p0, p1), hi = pk2bf(p2, p3);
                uint2 pw = {lo, hi};
                *(uint2*)&pl[(16 * it + il) * 64 + ((16 * jt + 4 * g) ^ rswz)] = pw;
            }
            lsum[it] += acc;
        }

        // ---- O[64c][64i] += V x P ----
        bf16x8 pb[4][2];
        #pragma unroll
        for (int it = 0; it < 4; ++it) {
            pb[it][0] = *(const bf16x8*)&pl[(16 * it + il) * 64 + e0];
            pb[it][1] = *(const bf16x8*)&pl[(16 * it + il) * 64 + e1];
        }
        #pragma unroll
        for (int ct = 0; ct < 4; ++ct) {
            bf16x8 va0 = *(const bf16x8*)&vt[(16 * ct + il) * 64 + e0];
            bf16x8 va1 = *(const bf16x8*)&vt[(16 * ct + il) * 64 + e1];
            #pragma unroll
            for (int it = 0; it < 4; ++it) {
                o[ct][it] = __builtin_amdgcn_mfma_f32_16x16x32_bf16(va0, pb[it][0], o[ct][it], 0, 0, 0);
                o[ct][it] = __builtin_amdgcn_mfma_f32_16x16x32_bf16(va1, pb[it][1], o[ct][it], 0, 0, 0);
            }
        }
    }

    // epilogue: cross-group lsum, normalize, store AOt[b][i][c]
    #pragma unroll
    for (int it = 0; it < 4; ++it) {
        lsum[it] += __shfl_xor(lsum[it], 16);
        lsum[it] += __shfl_xor(lsum[it], 32);
        float inv = 1.f / lsum[it];
        ushort_t* ao = AOt + ((size_t)(b * HW_ + iw + 16 * it + il) * C_ + c0 + 4 * g);
        #pragma unroll
        for (int ct = 0; ct < 4; ++ct) {
            f32x4 a = o[ct][it];
            short4v ov;
            ov.x = (short)f2bf(a.x * inv); ov.y = (short)f2bf(a.y * inv);
            ov.z = (short)f2bf(a.z * inv); ov.w = (short)f2bf(a.w * inv);
            *(short4v*)(ao + 16 * ct) = ov;
        }
    }
}

// ---------------- launch ----------------
extern "C" void kernel_launch(void* const* d_in, const int* in_sizes, int n_in,
                              void* d_out, int out_size, void* d_ws, size_t ws_size,
                              hipStream_t stream) {
    const float* x      = (const float*)d_in[0];
    const float* gamma  = (const float*)d_in[1];
    const float* beta   = (const float*)d_in[2];
    const float* w_qkv  = (const float*)d_in[3];
    const float* w_proj = (const float*)d_in[4];
    const float* b_proj = (const float*)d_in[5];
    float* out = (float*)d_out;
    char* ws = (char*)d_ws;

    float*    xn   = (float*)(ws + OFF_XN);
    ushort_t* xnb  = (ushort_t*)(ws + OFF_XNB);
    ushort_t* aot  = (ushort_t*)(ws + OFF_AOT);
    ushort_t* xnpb = (ushort_t*)(ws + OFF_XNPB);
    ushort_t* qt   = (ushort_t*)(ws + OFF_QT);
    ushort_t* kt   = (ushort_t*)(ws + OFF_KT);
    ushort_t* vb   = (ushort_t*)(ws + OFF_VB);
    ushort_t* wqb  = (ushort_t*)(ws + OFF_WQB);
    ushort_t* wpb  = (ushort_t*)(ws + OFF_WPB);
    float*    sums = (float*)(ws + OFF_SUM);
    float*    stat = (float*)(ws + OFF_STAT);

    const float QSCALE = 0.0625f * 1.44269504089f;   // C^-0.5 * log2(e)

    hipMemsetAsync(sums, 0, 2 * B_ * sizeof(float), stream);
    k_cvt<<<192, 256, 0, stream>>>(w_qkv, wqb, 3 * C_ * C_ / 4);
    k_cvt<<<64, 256, 0, stream>>>(w_proj, wpb, C_ * C_ / 4);
    k_reduce<<<256, 256, 0, stream>>>(x, sums);
    k_finalize<<<1, 64, 0, stream>>>(sums, stat);
    k_norm_tp<<<dim3(32, 4, 8), 256, 0, stream>>>(x, gamma, beta, stat, xn, xnb, xnpb);
    // Qt = (W_q @ xn)^T * QSCALE             M=256, N=4096
    k_mm<1><<<dim3(64, 1, 8), 256, 0, stream>>>(wqb, xnb, qt, HW_, QSCALE,
                                                0, nullptr, nullptr);
    // Kt = (W_k @ pool(xn))^T                M=256, N=1024
    k_mm<1><<<dim3(16, 1, 8), 256, 0, stream>>>(wqb + (size_t)C_ * C_, xnpb, kt, JP_,
                                                1.0f, 0, nullptr, nullptr);
    // V  = W_v @ pool(xn)                    M=256, N=1024
    k_mm<0><<<dim3(16, 1, 8), 256, 0, stream>>>(wqb + (size_t)2 * C_ * C_, xnpb, vb,
                                                JP_, 1.0f, (size_t)C_ * JP_,
                                                nullptr, nullptr);
    // attention -> AOt (aliases dead xnb)
    k_attn<<<dim3(16, 4, 8), 256, 0, stream>>>(qt, kt, vb, aot);
    // out = W_proj @ attn_out + b_proj + xn
    k_mm<2><<<dim3(64, 1, 8), 256, 0, stream>>>(wpb, aot, out, HW_, 1.0f,
                                                (size_t)C_ * HW_, b_proj, xn);
}

// Round 7
// 249.088 us; speedup vs baseline: 1.1286x; 1.0008x over previous
//
#include <hip/hip_runtime.h>
#include <hip/hip_bf16.h>
#include <math.h>

#define B_ 8
#define C_ 256
#define HW_ 4096
#define JP_ 1024
#define EPS_ 1e-5f

typedef __attribute__((ext_vector_type(8))) short bf16x8;   // 8 bf16 (4 VGPR) MFMA frag
typedef __attribute__((ext_vector_type(4))) short short4v;  // 8B packed bf16 store
typedef __attribute__((ext_vector_type(4))) float f32x4;    // MFMA accumulator
typedef unsigned short ushort_t;
typedef unsigned int uint_t;

__device__ __forceinline__ ushort_t f2bf(float f) {
    uint_t u = __float_as_uint(f);
    u += 0x7fffu + ((u >> 16) & 1u);       // round-nearest-even
    return (ushort_t)(u >> 16);
}
__device__ __forceinline__ float bf2f(ushort_t h) {
    return __uint_as_float(((uint_t)h) << 16);
}
__device__ __forceinline__ float exp2fast(float x) {
#if __has_builtin(__builtin_amdgcn_exp2f)
    return __builtin_amdgcn_exp2f(x);      // v_exp_f32: D = 2^x
#else
    return __expf(x * 0.69314718056f);
#endif
}
// pack 2 floats -> 2 bf16 in one u32 (compiler emits v_cvt_pk_bf16_f32)
__device__ __forceinline__ uint_t pk2bf(float a, float b) {
    __hip_bfloat162 h = __float22bfloat162_rn(float2{a, b});
    return *reinterpret_cast<uint_t*>(&h);
}
__device__ __forceinline__ bf16x8 mk8(uint_t a, uint_t b, uint_t c, uint_t d) {
    union { uint_t u[4]; bf16x8 v; } t;
    t.u[0] = a; t.u[1] = b; t.u[2] = c; t.u[3] = d;
    return t.v;
}

// ---------------- workspace layout (bytes) ----------------
static const size_t OFF_XN   = 0;            // xn   f32  [b][c][i]  32 MB
static const size_t OFF_XNB  = 33554432;     // xnb  bf16 [b][i][c]  16 MB
static const size_t OFF_AOT  = OFF_XNB;      // AOt aliases xnb (dead after q-GEMM)
static const size_t OFF_XNPB = 50331648;     // xnpb bf16 [b][j][c]   4 MB
static const size_t OFF_QT   = 54525952;     // Qt   bf16 [b][i][c]  16 MB (pre-scaled)
static const size_t OFF_KT   = 71303168;     // Kt   bf16 [b][j][c]   4 MB
static const size_t OFF_VB   = 75497472;     // V    bf16 [b][c][j]   4 MB
static const size_t OFF_WQB  = 79691776;
static const size_t OFF_WPB  = 80084992;
static const size_t OFF_SUM  = 80216064;     // 512 f32 partials (no atomics)
static const size_t OFF_STAT = 80218112;     // 16 f32 (mu, rs per batch)

// ---------------- K0: fp32 -> bf16 convert of both weight mats ----------------
__global__ __launch_bounds__(256) void k_cvt2(const float* __restrict__ wq,
                                              const float* __restrict__ wp,
                                              ushort_t* __restrict__ dq,
                                              ushort_t* __restrict__ dp) {
    int i = blockIdx.x * 256 + threadIdx.x;   // [0, 65536) float4 slots
    const float* src = (i < 49152) ? wq : wp;
    ushort_t*    dst = (i < 49152) ? dq : dp;
    int k = (i < 49152) ? i : i - 49152;
    float4 v = *(const float4*)(src + 4 * (size_t)k);
    short4v o;
    o.x = (short)f2bf(v.x); o.y = (short)f2bf(v.y);
    o.z = (short)f2bf(v.z); o.w = (short)f2bf(v.w);
    *(short4v*)(dst + 4 * (size_t)k) = o;
}

// ---------------- K1: per-batch sum/sumsq, stage 1 (deterministic, no atomics) --
// block bx = b*32 + slice writes its partial pair to psums[2*bx], psums[2*bx+1].
// Every slot written every call -> no init needed, bit-deterministic.
__global__ __launch_bounds__(256) void k_reduce(const float* __restrict__ x,
                                                float* __restrict__ psums) {
    int bx = blockIdx.x;
    int b = bx >> 5, slice = bx & 31;
    int t = threadIdx.x;
    const float4* xb = (const float4*)(x + (size_t)b * C_ * HW_);
    float s = 0.f, sq = 0.f;
    int base = slice * 8192 + t;
    #pragma unroll 4
    for (int r = 0; r < 32; ++r) {
        float4 v = xb[base + r * 256];
        s  += (v.x + v.y) + (v.z + v.w);
        sq += (v.x * v.x + v.y * v.y) + (v.z * v.z + v.w * v.w);
    }
    for (int off = 32; off; off >>= 1) {
        s  += __shfl_down(s, off);
        sq += __shfl_down(sq, off);
    }
    __shared__ float ls[4], lq[4];
    int wid = t >> 6;
    if ((t & 63) == 0) { ls[wid] = s; lq[wid] = sq; }
    __syncthreads();
    if (t == 0) {
        s  = (ls[0] + ls[1]) + (ls[2] + ls[3]);
        sq = (lq[0] + lq[1]) + (lq[2] + lq[3]);
        psums[2 * bx]     = s;
        psums[2 * bx + 1] = sq;
    }
}

// ---------------- K2: stage 2 -> mu / rsqrt per batch ----------------
__global__ void k_finalize(const float* __restrict__ psums, float* __restrict__ stat) {
    int b = threadIdx.x;
    if (b < B_) {
        float s = 0.f, sq = 0.f;
        #pragma unroll
        for (int i = 0; i < 32; ++i) {
            s  += psums[2 * (b * 32 + i)];
            sq += psums[2 * (b * 32 + i) + 1];
        }
        const float n = (float)((size_t)C_ * HW_);
        float mu = s / n;
        float var = sq / n - mu * mu;
        stat[2 * b] = mu;
        stat[2 * b + 1] = rsqrtf(var + EPS_);
    }
}

// ---------------- K3: norm + affine + LDS transpose + 2x2 pool ----------------
// pitch 88 (176B = 44 dwords): write-path bank stride -> <=2-way (free)
__global__ __launch_bounds__(256) void k_norm_tp(
        const float* __restrict__ x, const float* __restrict__ gamma,
        const float* __restrict__ beta, const float* __restrict__ stat,
        float* __restrict__ xn, ushort_t* __restrict__ xnb,
        ushort_t* __restrict__ xnpb) {
    __shared__ ushort_t T[128 * 88];
    int t = threadIdx.x;
    int r  = blockIdx.x;               // h-pair 0..31
    int c0 = blockIdx.y * 64;
    int b  = blockIdx.z;
    int i0 = r * 128;

    float mu = stat[2 * b], rs = stat[2 * b + 1];
    int cl = t >> 2;
    float gv = gamma[c0 + cl] * rs;
    float bv = beta[c0 + cl] - mu * gv;
    const float* xrow = x  + ((size_t)(b * C_ + c0 + cl) * HW_ + i0);
    float*      xnrow = xn + ((size_t)(b * C_ + c0 + cl) * HW_ + i0);
    #pragma unroll
    for (int u = 0; u < 8; ++u) {
        int f4 = (t & 3) + 4 * u;
        float4 v = *(const float4*)(xrow + f4 * 4);
        v.x = v.x * gv + bv; v.y = v.y * gv + bv;
        v.z = v.z * gv + bv; v.w = v.w * gv + bv;
        *(float4*)(xnrow + f4 * 4) = v;
        int ib = f4 * 4;
        T[(ib + 0) * 88 + cl] = f2bf(v.x);
        T[(ib + 1) * 88 + cl] = f2bf(v.y);
        T[(ib + 2) * 88 + cl] = f2bf(v.z);
        T[(ib + 3) * 88 + cl] = f2bf(v.w);
    }
    __syncthreads();
    {   // xnb[i][c], coalesced via transpose
        int i = t >> 1, ch = t & 1;
        ushort_t* dst = xnb + ((size_t)(b * HW_ + i0 + i) * C_ + c0 + ch * 32);
        #pragma unroll
        for (int u = 0; u < 4; ++u) {
            bf16x8 vv = *(const bf16x8*)&T[i * 88 + ch * 32 + u * 8];
            *(bf16x8*)(dst + u * 8) = vv;
        }
    }
    {   // 2x2 pool -> xnpb[j][c]
        int w2 = t >> 3, c8 = (t & 7) * 8;
        bf16x8 p0 = *(const bf16x8*)&T[(2 * w2 + 0) * 88 + c8];
        bf16x8 p1 = *(const bf16x8*)&T[(2 * w2 + 1) * 88 + c8];
        bf16x8 p2 = *(const bf16x8*)&T[(64 + 2 * w2 + 0) * 88 + c8];
        bf16x8 p3 = *(const bf16x8*)&T[(64 + 2 * w2 + 1) * 88 + c8];
        bf16x8 res;
        #pragma unroll
        for (int e = 0; e < 8; ++e) {
            float s = bf2f((ushort_t)p0[e]) + bf2f((ushort_t)p1[e]) +
                      bf2f((ushort_t)p2[e]) + bf2f((ushort_t)p3[e]);
            res[e] = (short)f2bf(0.25f * s);
        }
        int j = r * 32 + w2;
        *(bf16x8*)&xnpb[((size_t)(b * JP_) + j) * C_ + c0 + c8] = res;
    }
}

// ---------------- K4: bf16 MFMA GEMM, 2 m-subtiles/wave, m-block 128 -------------
// X [b][n][k] k-contiguous. Block: m 128 x n 64, 4 waves.
// MODE 0: Y bf16 [b][m][N];  MODE 1: Y bf16 [b][n][256]*scale;  MODE 2: f32 +bias+resid
template <int MODE>
__global__ __launch_bounds__(256, 3) void k_mm(
        const ushort_t* __restrict__ Wb, const ushort_t* __restrict__ Xb,
        void* __restrict__ Yp, int N, float scale, size_t strideY,
        const float* __restrict__ bias, const float* __restrict__ resid) {
    int t = threadIdx.x;
    int w = t >> 6, l = t & 63;
    int il = l & 15, g = l >> 4;
    int n0 = blockIdx.x * 64, m0 = blockIdx.y * 128, b = blockIdx.z;

    bf16x8 A[2][8];
    #pragma unroll
    for (int ms = 0; ms < 2; ++ms) {
        const ushort_t* wp = Wb + (size_t)(m0 + 64 * ms + 16 * w + il) * C_ + 8 * g;
        #pragma unroll
        for (int ks = 0; ks < 8; ++ks) A[ms][ks] = *(const bf16x8*)(wp + 32 * ks);
    }

    const ushort_t* xp = Xb + ((size_t)b * N + n0 + il) * C_ + 8 * g;
    f32x4 acc[2][4] = {};   // [ms][nt]
    #pragma unroll
    for (int ks = 0; ks < 8; ++ks) {
        bf16x8 bb[4];
        #pragma unroll
        for (int nt = 0; nt < 4; ++nt)
            bb[nt] = *(const bf16x8*)(xp + (size_t)16 * nt * C_ + 32 * ks);
        #pragma unroll
        for (int ms = 0; ms < 2; ++ms)
            #pragma unroll
            for (int nt = 0; nt < 4; ++nt)
                acc[ms][nt] = __builtin_amdgcn_mfma_f32_16x16x32_bf16(
                    A[ms][ks], bb[nt], acc[ms][nt], 0, 0, 0);
    }
    #pragma unroll
    for (int ms = 0; ms < 2; ++ms) {
        int mwg = m0 + 64 * ms + 16 * w + 4 * g;
        #pragma unroll
        for (int nt = 0; nt < 4; ++nt) {
            int n = n0 + 16 * nt + il;
            f32x4 a = acc[ms][nt];
            if (MODE == 0) {
                ushort_t* Y = (ushort_t*)Yp;
                size_t base = (size_t)b * strideY + (size_t)mwg * N + n;
                Y[base]                 = f2bf(a.x);
                Y[base + (size_t)N]     = f2bf(a.y);
                Y[base + (size_t)2 * N] = f2bf(a.z);
                Y[base + (size_t)3 * N] = f2bf(a.w);
            } else if (MODE == 1) {
                ushort_t* Y = (ushort_t*)Yp;
                short4v pv;
                pv.x = (short)f2bf(a.x * scale); pv.y = (short)f2bf(a.y * scale);
                pv.z = (short)f2bf(a.z * scale); pv.w = (short)f2bf(a.w * scale);
                *(short4v*)&Y[((size_t)b * N + n) * C_ + mwg] = pv;
            } else {
                float* Y = (float*)Yp;
                #pragma unroll
                for (int rr = 0; rr < 4; ++rr) {
                    int m = mwg + rr;
                    size_t yi = (size_t)b * strideY + (size_t)m * N + n;
                    float v = (rr == 0 ? a.x : rr == 1 ? a.y : rr == 2 ? a.z : a.w);
                    Y[yi] = v + bias[m] + resid[yi];
                }
            }
        }
    }
}

// ---------------- K5: MFMA flash attention, in-register P via sigma-staged K ----
// K rows staged at LDS row sigma(j) = 32(j>>5) + 16((j>>2)&1) + 4((j>>3)&3) + (j&3);
// then S^T D-frag at lane group g holds exactly P[j=8g+e][i] / P[32+8g+e][i] in
// register order -> PV B-frags built by cvt_pk packing, no P LDS round-trip.
// Plain launch_bounds(256): peak liveness ~190 VGPR; don't squeeze to 128 (spills).
__global__ __launch_bounds__(256) void k_attn(
        const ushort_t* __restrict__ Qt, const ushort_t* __restrict__ Kt,
        const ushort_t* __restrict__ Vb, ushort_t* __restrict__ AOt) {
    __shared__ ushort_t KV[2][8192];   // per buf: K(sigma rows)[64][64] @0, V[64c][64j] @4096
    int t = threadIdx.x;
    int w = t >> 6, l = t & 63;
    int il = l & 15, g = l >> 4;
    int b = blockIdx.z, h = blockIdx.y;
    int i0 = blockIdx.x * 256, c0 = h * 64;
    int iw = i0 + 64 * w;

    // persistent Q B-frags (Qt pre-scaled by C^-0.5 * log2(e))
    bf16x8 qf[4][2];
    {
        const ushort_t* qp = Qt + ((size_t)(b * HW_ + iw + il) * C_ + c0 + 8 * g);
        #pragma unroll
        for (int it = 0; it < 4; ++it) {
            qf[it][0] = *(const bf16x8*)(qp + (size_t)16 * it * C_);
            qf[it][1] = *(const bf16x8*)(qp + (size_t)16 * it * C_ + 32);
        }
    }

    // staging: wave covers K rows j0=16w+srow, j0+8 (dest rows sigma'd), V rows c
    int srow = l >> 3, sslot = l & 7;
    const ushort_t* kg = Kt + ((size_t)(b * JP_) + 16 * w + srow) * C_ + c0 + 8 * sslot;
    const ushort_t* vg = Vb + ((size_t)(b * C_) + c0 + 16 * w + srow) * JP_ + 8 * sslot;
    int sig0 = 32 * (w >> 1) + 8 * (w & 1) + 16 * ((srow >> 2) & 1) + (srow & 3);
    int sig1 = sig0 + 4;                               // sigma(j0+8) == sigma(j0)+4
    int kwr0 = sig0 * 64 + ((8 * sslot) ^ ((sig0 & 7) << 3));
    int kwr1 = sig1 * 64 + ((8 * sslot) ^ ((sig1 & 7) << 3));
    int vrow = 16 * w + srow;
    int vwr0 = vrow * 64 + ((8 * sslot) ^ ((vrow & 7) << 3));
    int vwr1 = vwr0 + 8 * 64;                          // (vrow+8)&7 == vrow&7

    int rswz = (il & 7) << 3;
    int e0 = (8 * g) ^ rswz;
    int e1 = (32 + 8 * g) ^ rswz;

    f32x4 o[4][4] = {};                 // [ct][it]
    float mold[4], lsum[4];
    #pragma unroll
    for (int it = 0; it < 4; ++it) { mold[it] = -3.0e38f; lsum[it] = 0.f; }

    // prologue: stage tile 0
    bf16x8 kr0 = *(const bf16x8*)(kg);
    bf16x8 kr1 = *(const bf16x8*)(kg + (size_t)8 * C_);
    bf16x8 vr0 = *(const bf16x8*)(vg);
    bf16x8 vr1 = *(const bf16x8*)(vg + (size_t)8 * JP_);
    *(bf16x8*)&KV[0][kwr0] = kr0;        *(bf16x8*)&KV[0][kwr1] = kr1;
    *(bf16x8*)&KV[0][4096 + vwr0] = vr0; *(bf16x8*)&KV[0][4096 + vwr1] = vr1;

    for (int tb = 0; tb < 16; ++tb) {
        int cur = tb & 1;
        if (tb < 15) {                  // issue next-tile global loads early
            int jb = (tb + 1) * 64;
            kr0 = *(const bf16x8*)(kg + (size_t)jb * C_);
            kr1 = *(const bf16x8*)(kg + (size_t)(jb + 8) * C_);
            vr0 = *(const bf16x8*)(vg + jb);
            vr1 = *(const bf16x8*)(vg + (size_t)8 * JP_ + jb);
        }
        __syncthreads();
        const ushort_t* kb = KV[cur];
        const ushort_t* vt = KV[cur] + 4096;

        // ---- S^T[64 sigma-rows][64 i] = K x Q ----
        f32x4 s[4][4];                  // [jt][it]
        #pragma unroll
        for (int jt = 0; jt < 4; ++jt) {
            bf16x8 ka0 = *(const bf16x8*)&kb[(16 * jt + il) * 64 + e0];
            bf16x8 ka1 = *(const bf16x8*)&kb[(16 * jt + il) * 64 + e1];
            #pragma unroll
            for (int it = 0; it < 4; ++it) {
                f32x4 z = {0.f, 0.f, 0.f, 0.f};
                s[jt][it] = __builtin_amdgcn_mfma_f32_16x16x32_bf16(ka0, qf[it][0], z, 0, 0, 0);
                s[jt][it] = __builtin_amdgcn_mfma_f32_16x16x32_bf16(ka1, qf[it][1], s[jt][it], 0, 0, 0);
            }
        }

        // write next tile into the other buffer (overlaps softmax VALU)
        if (tb < 15) {
            int nxt = cur ^ 1;
            *(bf16x8*)&KV[nxt][kwr0] = kr0;        *(bf16x8*)&KV[nxt][kwr1] = kr1;
            *(bf16x8*)&KV[nxt][4096 + vwr0] = vr0; *(bf16x8*)&KV[nxt][4096 + vwr1] = vr1;
        }

        // ---- per-lane online softmax (log2 domain), defer-max THR=8 ----
        float mxl[4];
        #pragma unroll
        for (int it = 0; it < 4; ++it) {
            float m01 = fmaxf(fmaxf(s[0][it].x, s[0][it].y), fmaxf(s[0][it].z, s[0][it].w));
            m01 = fmaxf(m01, fmaxf(fmaxf(s[1][it].x, s[1][it].y), fmaxf(s[1][it].z, s[1][it].w)));
            float m23 = fmaxf(fmaxf(s[2][it].x, s[2][it].y), fmaxf(s[2][it].z, s[2][it].w));
            m23 = fmaxf(m23, fmaxf(fmaxf(s[3][it].x, s[3][it].y), fmaxf(s[3][it].z, s[3][it].w)));
            mxl[it] = fmaxf(m01, m23);
        }
        float dmax = fmaxf(fmaxf(mxl[0] - mold[0], mxl[1] - mold[1]),
                           fmaxf(mxl[2] - mold[2], mxl[3] - mold[3]));
        if (!__all(dmax <= 8.0f)) {     // wave-uniform rescale branch
            #pragma unroll
            for (int it = 0; it < 4; ++it) {
                float mg = fmaxf(mxl[it], __shfl_xor(mxl[it], 16));
                mg = fmaxf(mg, __shfl_xor(mg, 32));
                float mn = fmaxf(mold[it], mg);
                float corr = exp2fast(mold[it] - mn);
                mold[it] = mn;
                lsum[it] *= corr;
                o[0][it] *= corr; o[1][it] *= corr; o[2][it] *= corr; o[3][it] *= corr;
            }
        }
        // exp + pack straight into PV B-frags (register order == j=8g+e by sigma)
        bf16x8 pb[4][2];
        #pragma unroll
        for (int it = 0; it < 4; ++it) {
            float m = mold[it];
            float acc = 0.f;
            uint_t pw[8];
            #pragma unroll
            for (int jt = 0; jt < 4; ++jt) {
                float p0 = exp2fast(s[jt][it].x - m);
                float p1 = exp2fast(s[jt][it].y - m);
                float p2 = exp2fast(s[jt][it].z - m);
                float p3 = exp2fast(s[jt][it].w - m);
                acc += (p0 + p1) + (p2 + p3);
                pw[2 * jt]     = pk2bf(p0, p1);
                pw[2 * jt + 1] = pk2bf(p2, p3);
            }
            lsum[it] += acc;
            pb[it][0] = mk8(pw[0], pw[1], pw[2], pw[3]);
            pb[it][1] = mk8(pw[4], pw[5], pw[6], pw[7]);
        }

        // ---- O[64c][64i] += V x P ----
        #pragma unroll
        for (int ct = 0; ct < 4; ++ct) {
            bf16x8 va0 = *(const bf16x8*)&vt[(16 * ct + il) * 64 + e0];
            bf16x8 va1 = *(const bf16x8*)&vt[(16 * ct + il) * 64 + e1];
            #pragma unroll
            for (int it = 0; it < 4; ++it) {
                o[ct][it] = __builtin_amdgcn_mfma_f32_16x16x32_bf16(va0, pb[it][0], o[ct][it], 0, 0, 0);
                o[ct][it] = __builtin_amdgcn_mfma_f32_16x16x32_bf16(va1, pb[it][1], o[ct][it], 0, 0, 0);
            }
        }
    }

    // epilogue: cross-group lsum, normalize, store AOt[b][i][c]
    #pragma unroll
    for (int it = 0; it < 4; ++it) {
        lsum[it] += __shfl_xor(lsum[it], 16);
        lsum[it] += __shfl_xor(lsum[it], 32);
        float inv = 1.f / lsum[it];
        ushort_t* ao = AOt + ((size_t)(b * HW_ + iw + 16 * it + il) * C_ + c0 + 4 * g);
        #pragma unroll
        for (int ct = 0; ct < 4; ++ct) {
            f32x4 a = o[ct][it];
            short4v ov;
            ov.x = (short)f2bf(a.x * inv); ov.y = (short)f2bf(a.y * inv);
            ov.z = (short)f2bf(a.z * inv); ov.w = (short)f2bf(a.w * inv);
            *(short4v*)(ao + 16 * ct) = ov;
        }
    }
}

// ---------------- launch ----------------
extern "C" void kernel_launch(void* const* d_in, const int* in_sizes, int n_in,
                              void* d_out, int out_size, void* d_ws, size_t ws_size,
                              hipStream_t stream) {
    const float* x      = (const float*)d_in[0];
    const float* gamma  = (const float*)d_in[1];
    const float* beta   = (const float*)d_in[2];
    const float* w_qkv  = (const float*)d_in[3];
    const float* w_proj = (const float*)d_in[4];
    const float* b_proj = (const float*)d_in[5];
    float* out = (float*)d_out;
    char* ws = (char*)d_ws;

    float*    xn   = (float*)(ws + OFF_XN);
    ushort_t* xnb  = (ushort_t*)(ws + OFF_XNB);
    ushort_t* aot  = (ushort_t*)(ws + OFF_AOT);
    ushort_t* xnpb = (ushort_t*)(ws + OFF_XNPB);
    ushort_t* qt   = (ushort_t*)(ws + OFF_QT);
    ushort_t* kt   = (ushort_t*)(ws + OFF_KT);
    ushort_t* vb   = (ushort_t*)(ws + OFF_VB);
    ushort_t* wqb  = (ushort_t*)(ws + OFF_WQB);
    ushort_t* wpb  = (ushort_t*)(ws + OFF_WPB);
    float*    psum = (float*)(ws + OFF_SUM);
    float*    stat = (float*)(ws + OFF_STAT);

    const float QSCALE = 0.0625f * 1.44269504089f;   // C^-0.5 * log2(e)

    k_cvt2<<<256, 256, 0, stream>>>(w_qkv, w_proj, wqb, wpb);
    k_reduce<<<256, 256, 0, stream>>>(x, psum);
    k_finalize<<<1, 64, 0, stream>>>(psum, stat);
    k_norm_tp<<<dim3(32, 4, 8), 256, 0, stream>>>(x, gamma, beta, stat, xn, xnb, xnpb);
    // Qt = (W_q @ xn)^T * QSCALE             M=256, N=4096
    k_mm<1><<<dim3(64, 2, 8), 256, 0, stream>>>(wqb, xnb, qt, HW_, QSCALE,
                                                0, nullptr, nullptr);
    // Kt = (W_k @ pool(xn))^T                M=256, N=1024
    k_mm<1><<<dim3(16, 2, 8), 256, 0, stream>>>(wqb + (size_t)C_ * C_, xnpb, kt, JP_,
                                                1.0f, 0, nullptr, nullptr);
    // V  = W_v @ pool(xn)                    M=256, N=1024
    k_mm<0><<<dim3(16, 2, 8), 256, 0, stream>>>(wqb + (size_t)2 * C_ * C_, xnpb, vb,
                                                JP_, 1.0f, (size_t)C_ * JP_,
                                                nullptr, nullptr);
    // attention -> AOt (aliases dead xnb)
    k_attn<<<dim3(16, 4, 8), 256, 0, stream>>>(qt, kt, vb, aot);
    // out = W_proj @ attn_out + b_proj + xn
    k_mm<2><<<dim3(64, 2, 8), 256, 0, stream>>>(wpb, aot, out, HW_, 1.0f,
                                                (size_t)C_ * HW_, b_proj, xn);
}

// Round 9
// 222.726 us; speedup vs baseline: 1.2622x; 1.1184x over previous
//
#include <hip/hip_runtime.h>
#include <hip/hip_bf16.h>
#include <math.h>

#define B_ 8
#define C_ 256
#define HW_ 4096
#define JP_ 1024
#define EPS_ 1e-5f

typedef __attribute__((ext_vector_type(8))) short bf16x8;   // 8 bf16 (4 VGPR) MFMA frag
typedef __attribute__((ext_vector_type(4))) short short4v;  // 8B packed bf16 store
typedef __attribute__((ext_vector_type(4))) float f32x4;    // MFMA accumulator
typedef unsigned short ushort_t;
typedef unsigned int uint_t;

__device__ __forceinline__ ushort_t f2bf(float f) {
    uint_t u = __float_as_uint(f);
    u += 0x7fffu + ((u >> 16) & 1u);       // round-nearest-even
    return (ushort_t)(u >> 16);
}
__device__ __forceinline__ float bf2f(ushort_t h) {
    return __uint_as_float(((uint_t)h) << 16);
}
__device__ __forceinline__ float exp2fast(float x) {
#if __has_builtin(__builtin_amdgcn_exp2f)
    return __builtin_amdgcn_exp2f(x);      // v_exp_f32: D = 2^x
#else
    return __expf(x * 0.69314718056f);
#endif
}
__device__ __forceinline__ uint_t pk2bf(float a, float b) {
    __hip_bfloat162 h = __float22bfloat162_rn(float2{a, b});
    return *reinterpret_cast<uint_t*>(&h);
}
__device__ __forceinline__ bf16x8 mk8(uint_t a, uint_t b, uint_t c, uint_t d) {
    union { uint_t u[4]; bf16x8 v; } t;
    t.u[0] = a; t.u[1] = b; t.u[2] = c; t.u[3] = d;
    return t.v;
}

// ---------------- workspace layout (bytes) ----------------
static const size_t OFF_XN   = 0;            // xn   f32  [b][c][i]  32 MB
static const size_t OFF_XNB  = 33554432;     // xnb  bf16 [b][i][c]  16 MB
static const size_t OFF_AOT  = OFF_XNB;      // AOt aliases xnb (dead after q-GEMM)
static const size_t OFF_XNPB = 50331648;     // xnpb bf16 [b][j][c]   4 MB
static const size_t OFF_QT   = 54525952;     // Qt   bf16 [b][i][c]  16 MB (pre-scaled)
static const size_t OFF_KT   = 71303168;     // Kt   bf16 [b][j][c]   4 MB
static const size_t OFF_VB   = 75497472;     // V    bf16 [b][c][j]   4 MB
static const size_t OFF_WQB  = 79691776;
static const size_t OFF_WPB  = 80084992;
static const size_t OFF_SUM  = 80216064;     // 512 f32 partials (no atomics)

// ---------------- K1: fused weight-convert (blocks 0..255) + reduce (256..511) --
__global__ __launch_bounds__(256) void k_init(
        const float* __restrict__ wq, const float* __restrict__ wp,
        ushort_t* __restrict__ dq, ushort_t* __restrict__ dp,
        const float* __restrict__ x, float* __restrict__ psums) {
    int bx = blockIdx.x;
    int t = threadIdx.x;
    if (bx < 256) {                        // ---- weight convert ----
        int i = bx * 256 + t;              // [0, 65536) float4 slots
        const float* src = (i < 49152) ? wq : wp;
        ushort_t*    dst = (i < 49152) ? dq : dp;
        int k = (i < 49152) ? i : i - 49152;
        float4 v = *(const float4*)(src + 4 * (size_t)k);
        short4v o;
        o.x = (short)f2bf(v.x); o.y = (short)f2bf(v.y);
        o.z = (short)f2bf(v.z); o.w = (short)f2bf(v.w);
        *(short4v*)(dst + 4 * (size_t)k) = o;
    } else {                               // ---- per-batch partial sum/sumsq ----
        int bb = bx - 256;
        int b = bb >> 5, slice = bb & 31;
        const float4* xb = (const float4*)(x + (size_t)b * C_ * HW_);
        float s = 0.f, sq = 0.f;
        int base = slice * 8192 + t;
        #pragma unroll 4
        for (int r = 0; r < 32; ++r) {
            float4 v = xb[base + r * 256];
            s  += (v.x + v.y) + (v.z + v.w);
            sq += (v.x * v.x + v.y * v.y) + (v.z * v.z + v.w * v.w);
        }
        for (int off = 32; off; off >>= 1) {
            s  += __shfl_down(s, off);
            sq += __shfl_down(sq, off);
        }
        __shared__ float ls[4], lq[4];
        int wid = t >> 6;
        if ((t & 63) == 0) { ls[wid] = s; lq[wid] = sq; }
        __syncthreads();
        if (t == 0) {
            s  = (ls[0] + ls[1]) + (ls[2] + ls[3]);
            sq = (lq[0] + lq[1]) + (lq[2] + lq[3]);
            psums[2 * bb]     = s;
            psums[2 * bb + 1] = sq;
        }
    }
}

// ---------------- K2: norm + affine + LDS transpose + 2x2 pool (finalize fused) --
__global__ __launch_bounds__(256) void k_norm_tp(
        const float* __restrict__ x, const float* __restrict__ gamma,
        const float* __restrict__ beta, const float* __restrict__ psums,
        float* __restrict__ xn, ushort_t* __restrict__ xnb,
        ushort_t* __restrict__ xnpb) {
    __shared__ ushort_t T[128 * 88];
    int t = threadIdx.x;
    int r  = blockIdx.x;               // h-pair 0..31
    int c0 = blockIdx.y * 64;
    int b  = blockIdx.z;
    int i0 = r * 128;

    float s = 0.f, sq = 0.f;
    #pragma unroll
    for (int i = 0; i < 32; ++i) {
        s  += psums[2 * (b * 32 + i)];
        sq += psums[2 * (b * 32 + i) + 1];
    }
    const float n = (float)((size_t)C_ * HW_);
    float mu = s / n;
    float var = sq / n - mu * mu;
    float rs = rsqrtf(var + EPS_);

    int cl = t >> 2;
    float gv = gamma[c0 + cl] * rs;
    float bv = beta[c0 + cl] - mu * gv;
    const float* xrow = x  + ((size_t)(b * C_ + c0 + cl) * HW_ + i0);
    float*      xnrow = xn + ((size_t)(b * C_ + c0 + cl) * HW_ + i0);
    #pragma unroll
    for (int u = 0; u < 8; ++u) {
        int f4 = (t & 3) + 4 * u;
        float4 v = *(const float4*)(xrow + f4 * 4);
        v.x = v.x * gv + bv; v.y = v.y * gv + bv;
        v.z = v.z * gv + bv; v.w = v.w * gv + bv;
        *(float4*)(xnrow + f4 * 4) = v;
        int ib = f4 * 4;
        T[(ib + 0) * 88 + cl] = f2bf(v.x);
        T[(ib + 1) * 88 + cl] = f2bf(v.y);
        T[(ib + 2) * 88 + cl] = f2bf(v.z);
        T[(ib + 3) * 88 + cl] = f2bf(v.w);
    }
    __syncthreads();
    {   // xnb[i][c], coalesced via transpose
        int i = t >> 1, ch = t & 1;
        ushort_t* dst = xnb + ((size_t)(b * HW_ + i0 + i) * C_ + c0 + ch * 32);
        #pragma unroll
        for (int u = 0; u < 4; ++u) {
            bf16x8 vv = *(const bf16x8*)&T[i * 88 + ch * 32 + u * 8];
            *(bf16x8*)(dst + u * 8) = vv;
        }
    }
    {   // 2x2 pool -> xnpb[j][c]
        int w2 = t >> 3, c8 = (t & 7) * 8;
        bf16x8 p0 = *(const bf16x8*)&T[(2 * w2 + 0) * 88 + c8];
        bf16x8 p1 = *(const bf16x8*)&T[(2 * w2 + 1) * 88 + c8];
        bf16x8 p2 = *(const bf16x8*)&T[(64 + 2 * w2 + 0) * 88 + c8];
        bf16x8 p3 = *(const bf16x8*)&T[(64 + 2 * w2 + 1) * 88 + c8];
        bf16x8 res;
        #pragma unroll
        for (int e = 0; e < 8; ++e) {
            float sm = bf2f((ushort_t)p0[e]) + bf2f((ushort_t)p1[e]) +
                       bf2f((ushort_t)p2[e]) + bf2f((ushort_t)p3[e]);
            res[e] = (short)f2bf(0.25f * sm);
        }
        int j = r * 32 + w2;
        *(bf16x8*)&xnpb[((size_t)(b * JP_) + j) * C_ + c0 + c8] = res;
    }
}

// ---------------- K3: fused Q/K/V GEMMs (one launch, 192 blocks/batch) ----------
// bx<128: Qt (transposed store, scaled); 128..159: Kt (transposed); 160..191: V.
__global__ __launch_bounds__(256, 3) void k_qkv(
        const ushort_t* __restrict__ wqb, const ushort_t* __restrict__ xnb,
        const ushort_t* __restrict__ xnpb, ushort_t* __restrict__ qt,
        ushort_t* __restrict__ kt, ushort_t* __restrict__ vb, float qscale) {
    int bx = blockIdx.x, b = blockIdx.z;
    int t = threadIdx.x;
    int w = t >> 6, l = t & 63;
    int il = l & 15, g = l >> 4;

    const ushort_t *Wb, *Xb;
    ushort_t* Y;
    int N, n0, m0, mode;
    float scale;
    if (bx < 128) {
        Wb = wqb; Xb = xnb; Y = qt; N = HW_; scale = qscale; mode = 1;
        n0 = (bx & 63) * 64; m0 = (bx >> 6) * 128;
    } else if (bx < 160) {
        int rr = bx - 128;
        Wb = wqb + (size_t)C_ * C_; Xb = xnpb; Y = kt; N = JP_; scale = 1.f; mode = 1;
        n0 = (rr & 15) * 64; m0 = (rr >> 4) * 128;
    } else {
        int rr = bx - 160;
        Wb = wqb + (size_t)2 * C_ * C_; Xb = xnpb; Y = vb; N = JP_; scale = 1.f; mode = 0;
        n0 = (rr & 15) * 64; m0 = (rr >> 4) * 128;
    }

    bf16x8 A[2][8];
    #pragma unroll
    for (int ms = 0; ms < 2; ++ms) {
        const ushort_t* wp = Wb + (size_t)(m0 + 64 * ms + 16 * w + il) * C_ + 8 * g;
        #pragma unroll
        for (int ks = 0; ks < 8; ++ks) A[ms][ks] = *(const bf16x8*)(wp + 32 * ks);
    }
    const ushort_t* xp = Xb + ((size_t)b * N + n0 + il) * C_ + 8 * g;
    f32x4 acc[2][4] = {};
    #pragma unroll
    for (int ks = 0; ks < 8; ++ks) {
        bf16x8 bb[4];
        #pragma unroll
        for (int nt = 0; nt < 4; ++nt)
            bb[nt] = *(const bf16x8*)(xp + (size_t)16 * nt * C_ + 32 * ks);
        #pragma unroll
        for (int ms = 0; ms < 2; ++ms)
            #pragma unroll
            for (int nt = 0; nt < 4; ++nt)
                acc[ms][nt] = __builtin_amdgcn_mfma_f32_16x16x32_bf16(
                    A[ms][ks], bb[nt], acc[ms][nt], 0, 0, 0);
    }
    #pragma unroll
    for (int ms = 0; ms < 2; ++ms) {
        int mwg = m0 + 64 * ms + 16 * w + 4 * g;
        #pragma unroll
        for (int nt = 0; nt < 4; ++nt) {
            int nn = n0 + 16 * nt + il;
            f32x4 a = acc[ms][nt];
            if (mode == 1) {
                short4v pv;
                pv.x = (short)f2bf(a.x * scale); pv.y = (short)f2bf(a.y * scale);
                pv.z = (short)f2bf(a.z * scale); pv.w = (short)f2bf(a.w * scale);
                *(short4v*)&Y[((size_t)b * N + nn) * C_ + mwg] = pv;
            } else {
                size_t base = ((size_t)b * C_ + mwg) * (size_t)N + nn;
                Y[base]                 = f2bf(a.x);
                Y[base + (size_t)N]     = f2bf(a.y);
                Y[base + (size_t)2 * N] = f2bf(a.z);
                Y[base + (size_t)3 * N] = f2bf(a.w);
            }
        }
    }
}

// ---------------- K4 (proj): bf16 MFMA GEMM, f32 out + bias + resid -------------
__global__ __launch_bounds__(256, 3) void k_mm2(
        const ushort_t* __restrict__ Wb, const ushort_t* __restrict__ Xb,
        float* __restrict__ Y, const float* __restrict__ bias,
        const float* __restrict__ resid) {
    const int N = HW_;
    int t = threadIdx.x;
    int w = t >> 6, l = t & 63;
    int il = l & 15, g = l >> 4;
    int n0 = blockIdx.x * 64, m0 = blockIdx.y * 128, b = blockIdx.z;

    bf16x8 A[2][8];
    #pragma unroll
    for (int ms = 0; ms < 2; ++ms) {
        const ushort_t* wp = Wb + (size_t)(m0 + 64 * ms + 16 * w + il) * C_ + 8 * g;
        #pragma unroll
        for (int ks = 0; ks < 8; ++ks) A[ms][ks] = *(const bf16x8*)(wp + 32 * ks);
    }
    const ushort_t* xp = Xb + ((size_t)b * N + n0 + il) * C_ + 8 * g;
    f32x4 acc[2][4] = {};
    #pragma unroll
    for (int ks = 0; ks < 8; ++ks) {
        bf16x8 bb[4];
        #pragma unroll
        for (int nt = 0; nt < 4; ++nt)
            bb[nt] = *(const bf16x8*)(xp + (size_t)16 * nt * C_ + 32 * ks);
        #pragma unroll
        for (int ms = 0; ms < 2; ++ms)
            #pragma unroll
            for (int nt = 0; nt < 4; ++nt)
                acc[ms][nt] = __builtin_amdgcn_mfma_f32_16x16x32_bf16(
                    A[ms][ks], bb[nt], acc[ms][nt], 0, 0, 0);
    }
    #pragma unroll
    for (int ms = 0; ms < 2; ++ms) {
        int mwg = m0 + 64 * ms + 16 * w + 4 * g;
        #pragma unroll
        for (int nt = 0; nt < 4; ++nt) {
            int nn = n0 + 16 * nt + il;
            f32x4 a = acc[ms][nt];
            #pragma unroll
            for (int rr = 0; rr < 4; ++rr) {
                int m = mwg + rr;
                size_t yi = ((size_t)b * C_ + m) * (size_t)N + nn;
                float v = (rr == 0 ? a.x : rr == 1 ? a.y : rr == 2 ? a.z : a.w);
                Y[yi] = v + bias[m] + resid[yi];
            }
        }
    }
}

// ---------------- K5: MFMA flash attention, 32 q/wave, 4 blocks/CU ----------
// sigma-staged K (in-register P), XOR-swizzled LDS; defer-max log2 softmax.
// 32 q/wave halves s/o/qf state -> ~125 VGPR; (256,4) = 4 waves/SIMD.
__global__ __launch_bounds__(256, 4) void k_attn(
        const ushort_t* __restrict__ Qt, const ushort_t* __restrict__ Kt,
        const ushort_t* __restrict__ Vb, ushort_t* __restrict__ AOt) {
    __shared__ ushort_t KV[2][8192];   // per buf: K(sigma rows)[64][64] @0, V[64c][64j] @4096
    int t = threadIdx.x;
    int w = t >> 6, l = t & 63;
    int il = l & 15, g = l >> 4;
    int b = blockIdx.z, h = blockIdx.y;
    int i0 = blockIdx.x * 128, c0 = h * 64;
    int iw = i0 + 32 * w;

    // persistent Q B-frags (Qt pre-scaled by C^-0.5 * log2(e))
    bf16x8 qf[2][2];
    {
        const ushort_t* qp = Qt + ((size_t)(b * HW_ + iw + il) * C_ + c0 + 8 * g);
        #pragma unroll
        for (int it = 0; it < 2; ++it) {
            qf[it][0] = *(const bf16x8*)(qp + (size_t)16 * it * C_);
            qf[it][1] = *(const bf16x8*)(qp + (size_t)16 * it * C_ + 32);
        }
    }

    // staging: wave covers K rows j0=16w+srow, j0+8 (dest rows sigma'd), V rows c
    int srow = l >> 3, sslot = l & 7;
    const ushort_t* kg = Kt + ((size_t)(b * JP_) + 16 * w + srow) * C_ + c0 + 8 * sslot;
    const ushort_t* vg = Vb + ((size_t)(b * C_) + c0 + 16 * w + srow) * JP_ + 8 * sslot;
    int sig0 = 32 * (w >> 1) + 8 * (w & 1) + 16 * ((srow >> 2) & 1) + (srow & 3);
    int sig1 = sig0 + 4;                               // sigma(j0+8) == sigma(j0)+4
    int kwr0 = sig0 * 64 + ((8 * sslot) ^ ((sig0 & 7) << 3));
    int kwr1 = sig1 * 64 + ((8 * sslot) ^ ((sig1 & 7) << 3));
    int vrow = 16 * w + srow;
    int vwr0 = vrow * 64 + ((8 * sslot) ^ ((vrow & 7) << 3));
    int vwr1 = vwr0 + 8 * 64;                          // (vrow+8)&7 == vrow&7

    int rswz = (il & 7) << 3;
    int e0 = (8 * g) ^ rswz;
    int e1 = (32 + 8 * g) ^ rswz;

    f32x4 o[4][2] = {};                 // [ct][it]
    float mold[2], lsum[2];
    #pragma unroll
    for (int it = 0; it < 2; ++it) { mold[it] = -3.0e38f; lsum[it] = 0.f; }

    // prologue: stage tile 0
    bf16x8 kr0 = *(const bf16x8*)(kg);
    bf16x8 kr1 = *(const bf16x8*)(kg + (size_t)8 * C_);
    bf16x8 vr0 = *(const bf16x8*)(vg);
    bf16x8 vr1 = *(const bf16x8*)(vg + (size_t)8 * JP_);
    *(bf16x8*)&KV[0][kwr0] = kr0;        *(bf16x8*)&KV[0][kwr1] = kr1;
    *(bf16x8*)&KV[0][4096 + vwr0] = vr0; *(bf16x8*)&KV[0][4096 + vwr1] = vr1;

    for (int tb = 0; tb < 16; ++tb) {
        int cur = tb & 1;
        if (tb < 15) {                  // issue next-tile global loads early
            int jb = (tb + 1) * 64;
            kr0 = *(const bf16x8*)(kg + (size_t)jb * C_);
            kr1 = *(const bf16x8*)(kg + (size_t)(jb + 8) * C_);
            vr0 = *(const bf16x8*)(vg + jb);
            vr1 = *(const bf16x8*)(vg + (size_t)8 * JP_ + jb);
        }
        __syncthreads();
        const ushort_t* kb = KV[cur];
        const ushort_t* vt = KV[cur] + 4096;

        // ---- S^T[64 sigma-rows][32 i] = K x Q ----
        f32x4 s[4][2];                  // [jt][it]
        #pragma unroll
        for (int jt = 0; jt < 4; ++jt) {
            bf16x8 ka0 = *(const bf16x8*)&kb[(16 * jt + il) * 64 + e0];
            bf16x8 ka1 = *(const bf16x8*)&kb[(16 * jt + il) * 64 + e1];
            #pragma unroll
            for (int it = 0; it < 2; ++it) {
                f32x4 z = {0.f, 0.f, 0.f, 0.f};
                s[jt][it] = __builtin_amdgcn_mfma_f32_16x16x32_bf16(ka0, qf[it][0], z, 0, 0, 0);
                s[jt][it] = __builtin_amdgcn_mfma_f32_16x16x32_bf16(ka1, qf[it][1], s[jt][it], 0, 0, 0);
            }
        }

        // write next tile into the other buffer (overlaps softmax VALU)
        if (tb < 15) {
            int nxt = cur ^ 1;
            *(bf16x8*)&KV[nxt][kwr0] = kr0;        *(bf16x8*)&KV[nxt][kwr1] = kr1;
            *(bf16x8*)&KV[nxt][4096 + vwr0] = vr0; *(bf16x8*)&KV[nxt][4096 + vwr1] = vr1;
        }

        // ---- per-lane online softmax (log2 domain), defer-max THR=8 ----
        float mxl[2];
        #pragma unroll
        for (int it = 0; it < 2; ++it) {
            float m01 = fmaxf(fmaxf(s[0][it].x, s[0][it].y), fmaxf(s[0][it].z, s[0][it].w));
            m01 = fmaxf(m01, fmaxf(fmaxf(s[1][it].x, s[1][it].y), fmaxf(s[1][it].z, s[1][it].w)));
            float m23 = fmaxf(fmaxf(s[2][it].x, s[2][it].y), fmaxf(s[2][it].z, s[2][it].w));
            m23 = fmaxf(m23, fmaxf(fmaxf(s[3][it].x, s[3][it].y), fmaxf(s[3][it].z, s[3][it].w)));
            mxl[it] = fmaxf(m01, m23);
        }
        float dmax = fmaxf(mxl[0] - mold[0], mxl[1] - mold[1]);
        if (!__all(dmax <= 8.0f)) {     // wave-uniform rescale branch
            #pragma unroll
            for (int it = 0; it < 2; ++it) {
                float mg = fmaxf(mxl[it], __shfl_xor(mxl[it], 16));
                mg = fmaxf(mg, __shfl_xor(mg, 32));
                float mn = fmaxf(mold[it], mg);
                float corr = exp2fast(mold[it] - mn);
                mold[it] = mn;
                lsum[it] *= corr;
                o[0][it] *= corr; o[1][it] *= corr; o[2][it] *= corr; o[3][it] *= corr;
            }
        }
        // exp + pack straight into PV B-frags (register order == j=8g+e by sigma)
        bf16x8 pb[2][2];
        #pragma unroll
        for (int it = 0; it < 2; ++it) {
            float m = mold[it];
            float acc = 0.f;
            uint_t pw[8];
            #pragma unroll
            for (int jt = 0; jt < 4; ++jt) {
                float p0 = exp2fast(s[jt][it].x - m);
                float p1 = exp2fast(s[jt][it].y - m);
                float p2 = exp2fast(s[jt][it].z - m);
                float p3 = exp2fast(s[jt][it].w - m);
                acc += (p0 + p1) + (p2 + p3);
                pw[2 * jt]     = pk2bf(p0, p1);
                pw[2 * jt + 1] = pk2bf(p2, p3);
            }
            lsum[it] += acc;
            pb[it][0] = mk8(pw[0], pw[1], pw[2], pw[3]);
            pb[it][1] = mk8(pw[4], pw[5], pw[6], pw[7]);
        }

        // ---- O[64c][32i] += V x P ----
        #pragma unroll
        for (int ct = 0; ct < 4; ++ct) {
            bf16x8 va0 = *(const bf16x8*)&vt[(16 * ct + il) * 64 + e0];
            bf16x8 va1 = *(const bf16x8*)&vt[(16 * ct + il) * 64 + e1];
            #pragma unroll
            for (int it = 0; it < 2; ++it) {
                o[ct][it] = __builtin_amdgcn_mfma_f32_16x16x32_bf16(va0, pb[it][0], o[ct][it], 0, 0, 0);
                o[ct][it] = __builtin_amdgcn_mfma_f32_16x16x32_bf16(va1, pb[it][1], o[ct][it], 0, 0, 0);
            }
        }
    }

    // epilogue: cross-group lsum, normalize, store AOt[b][i][c]
    #pragma unroll
    for (int it = 0; it < 2; ++it) {
        lsum[it] += __shfl_xor(lsum[it], 16);
        lsum[it] += __shfl_xor(lsum[it], 32);
        float inv = 1.f / lsum[it];
        ushort_t* ao = AOt + ((size_t)(b * HW_ + iw + 16 * it + il) * C_ + c0 + 4 * g);
        #pragma unroll
        for (int ct = 0; ct < 4; ++ct) {
            f32x4 a = o[ct][it];
            short4v ov;
            ov.x = (short)f2bf(a.x * inv); ov.y = (short)f2bf(a.y * inv);
            ov.z = (short)f2bf(a.z * inv); ov.w = (short)f2bf(a.w * inv);
            *(short4v*)(ao + 16 * ct) = ov;
        }
    }
}

// ---------------- launch ----------------
extern "C" void kernel_launch(void* const* d_in, const int* in_sizes, int n_in,
                              void* d_out, int out_size, void* d_ws, size_t ws_size,
                              hipStream_t stream) {
    const float* x      = (const float*)d_in[0];
    const float* gamma  = (const float*)d_in[1];
    const float* beta   = (const float*)d_in[2];
    const float* w_qkv  = (const float*)d_in[3];
    const float* w_proj = (const float*)d_in[4];
    const float* b_proj = (const float*)d_in[5];
    float* out = (float*)d_out;
    char* ws = (char*)d_ws;

    float*    xn   = (float*)(ws + OFF_XN);
    ushort_t* xnb  = (ushort_t*)(ws + OFF_XNB);
    ushort_t* aot  = (ushort_t*)(ws + OFF_AOT);
    ushort_t* xnpb = (ushort_t*)(ws + OFF_XNPB);
    ushort_t* qt   = (ushort_t*)(ws + OFF_QT);
    ushort_t* kt   = (ushort_t*)(ws + OFF_KT);
    ushort_t* vb   = (ushort_t*)(ws + OFF_VB);
    ushort_t* wqb  = (ushort_t*)(ws + OFF_WQB);
    ushort_t* wpb  = (ushort_t*)(ws + OFF_WPB);
    float*    psum = (float*)(ws + OFF_SUM);

    const float QSCALE = 0.0625f * 1.44269504089f;   // C^-0.5 * log2(e)

    k_init<<<512, 256, 0, stream>>>(w_qkv, w_proj, wqb, wpb, x, psum);
    k_norm_tp<<<dim3(32, 4, 8), 256, 0, stream>>>(x, gamma, beta, psum, xn, xnb, xnpb);
    k_qkv<<<dim3(192, 1, 8), 256, 0, stream>>>(wqb, xnb, xnpb, qt, kt, vb, QSCALE);
    k_attn<<<dim3(32, 4, 8), 256, 0, stream>>>(qt, kt, vb, aot);
    k_mm2<<<dim3(64, 2, 8), 256, 0, stream>>>(wpb, aot, out, b_proj, xn);
}